// Round 5
// baseline (314.379 us; speedup 1.0000x reference)
//
#include <hip/hip_runtime.h>
#include <hip/hip_bf16.h>
#include <stdint.h>

// Problem constants
#define NB 4
#define NT 2048
#define NC 1024
#define NH 16
#define NHD 64
#define NM (NB*NT)   // 8192 rows

typedef __attribute__((ext_vector_type(8))) __bf16 bf16x8;
typedef __attribute__((ext_vector_type(4))) float floatx4;
typedef __attribute__((ext_vector_type(4))) unsigned int uintx4;

#define AS1(p) ((const __attribute__((address_space(1))) void*)(p))
#define AS3(p) ((__attribute__((address_space(3))) void*)(p))

__device__ __forceinline__ unsigned short f2bf(float f) {
    union { float f; unsigned int u; } v; v.f = f;
    unsigned int u = v.u;
    return (unsigned short)((u + 0x7FFFu + ((u >> 16) & 1u)) >> 16);
}

// ---------------- cast fp32 -> bf16 (vectorized x4) ----------------
__global__ void cast_kernel(const float* __restrict__ in,
                            unsigned short* __restrict__ out, int n4) {
    int i = blockIdx.x * blockDim.x + threadIdx.x;
    if (i >= n4) return;
    floatx4 v = ((const floatx4*)in)[i];
    ushort4 o;
    o.x = f2bf(v.x); o.y = f2bf(v.y); o.z = f2bf(v.z); o.w = f2bf(v.w);
    ((ushort4*)out)[i] = o;
}

__global__ void cast4_kernel(const float* __restrict__ w0, const float* __restrict__ w1,
                             const float* __restrict__ w2, const float* __restrict__ w3,
                             unsigned short* __restrict__ o0, unsigned short* __restrict__ o1,
                             unsigned short* __restrict__ o2, unsigned short* __restrict__ o3,
                             int n4) {
    int i = blockIdx.x * blockDim.x + threadIdx.x;
    if (i >= n4) return;
    const float* in; unsigned short* out;
    switch (blockIdx.y) {
        case 0: in = w0; out = o0; break;
        case 1: in = w1; out = o1; break;
        case 2: in = w2; out = o2; break;
        default: in = w3; out = o3; break;
    }
    floatx4 v = ((const floatx4*)in)[i];
    ushort4 o;
    o.x = f2bf(v.x); o.y = f2bf(v.y); o.z = f2bf(v.z); o.w = f2bf(v.w);
    ((ushort4*)out)[i] = o;
}

// ---------------- GEMM core: Out = (A @ W^T + bias) * oscale ----------------
// LDS staged in MFMA fragment order via global_load_lds width=16:
// lane (quad=lane>>4, l16=lane&15) loads global [row=l16][k=quad*8..+7];
// LDS subtile block (16 rows x 32 k) = 512 shorts, fragment read for any lane
// is base + lane*8 shorts -> contiguous 1KB wave read, bank-conflict-free.
// BK=64 (two k-steps per barrier) halves barrier-drain cost.
// mode 0: Out fp32 row-major MxN (final projection)
// mode 1: Out bf16 in MFMA A/B-fragment order for Q/K
// mode 2: Out bf16 in MFMA B-fragment order for V (PV operand)
#define TM 128
#define TN 128
#define BK 64

__device__ __forceinline__ void gemm_core(
    const unsigned short* __restrict__ A,
    const unsigned short* __restrict__ W,
    const float* __restrict__ bias,
    void* __restrict__ Out,
    unsigned short* As, unsigned short* Bs,
    int m_base, int n_base, int N_out, int K, int mode, float oscale)
{
    const int tid  = threadIdx.x;
    const int lane = tid & 63;
    const int wv   = tid >> 6;
    const int quad = lane >> 4;
    const int l16  = lane & 15;
    const int wm = (wv >> 1) * 64;
    const int wn = (wv & 1) * 64;

    floatx4 acc[4][4];
    #pragma unroll
    for (int i = 0; i < 4; ++i)
        #pragma unroll
        for (int j = 0; j < 4; ++j)
            acc[i][j] = (floatx4){0.f, 0.f, 0.f, 0.f};

    const int kTiles = K / BK;

    // staging: lane (quad,l16) -> row l16 (of each 16-row subtile), col quad*8
    const unsigned short* Ab = A + (size_t)(m_base + wv*32 + l16) * K + quad*8;
    const unsigned short* Wb = W + (size_t)(n_base + wv*32 + l16) * K + quad*8;

    for (int kt = 0; kt < kTiles; ++kt) {
        const int k0 = kt * BK;
        __syncthreads();
        #pragma unroll
        for (int i = 0; i < 2; ++i) {           // subtile (16 rows)
            #pragma unroll
            for (int kk = 0; kk < 2; ++kk) {    // k-step half
                __builtin_amdgcn_global_load_lds(
                    AS1(Ab + (size_t)i*16*K + k0 + kk*32),
                    AS3(&As[(wv*2 + i)*1024 + kk*512]), 16, 0, 0);
                __builtin_amdgcn_global_load_lds(
                    AS1(Wb + (size_t)i*16*K + k0 + kk*32),
                    AS3(&Bs[(wv*2 + i)*1024 + kk*512]), 16, 0, 0);
            }
        }
        __syncthreads();

        #pragma unroll
        for (int kk = 0; kk < 2; ++kk) {
            bf16x8 af[4], bfr[4];
            #pragma unroll
            for (int mi = 0; mi < 4; ++mi)
                af[mi] = *(const bf16x8*)&As[((wm >> 4) + mi)*1024 + kk*512 + lane*8];
            #pragma unroll
            for (int ni = 0; ni < 4; ++ni)
                bfr[ni] = *(const bf16x8*)&Bs[((wn >> 4) + ni)*1024 + kk*512 + lane*8];

            #pragma unroll
            for (int mi = 0; mi < 4; ++mi)
                #pragma unroll
                for (int ni = 0; ni < 4; ++ni)
                    acc[mi][ni] = __builtin_amdgcn_mfma_f32_16x16x32_bf16(
                        af[mi], bfr[ni], acc[mi][ni], 0, 0, 0);
        }
    }

    // epilogue: C/D layout col = lane&15, row = quad*4 + reg
    #pragma unroll
    for (int mi = 0; mi < 4; ++mi) {
        #pragma unroll
        for (int ni = 0; ni < 4; ++ni) {
            const int col = n_base + wn + ni*16 + l16;
            const float bv = bias[col & 1023];
            #pragma unroll
            for (int r = 0; r < 4; ++r) {
                const int row = m_base + wm + mi*16 + quad*4 + r;
                const float v = (acc[mi][ni][r] + bv) * oscale;
                if (mode == 0) {
                    ((float*)Out)[(size_t)row * N_out + col] = v;
                } else if (mode == 1) {
                    const int bb = row >> 11, t = row & (NT - 1);
                    const int h  = (col >> 6) & (NH - 1), d = col & 63;
                    const int bh = bb * NH + h;
                    const size_t idx =
                        ((size_t)((bh*128 + (t >> 4))*2 + (d >> 5)))*512
                        + (size_t)((((d >> 3) & 3)*16 + (t & 15))*8 + (d & 7));
                    ((unsigned short*)Out)[idx] = f2bf(v);
                } else {
                    const int bb = row >> 11, t = row & (NT - 1);
                    const int h  = (col >> 6) & (NH - 1), hd = col & 63;
                    const int bh = bb * NH + h;
                    const size_t idx =
                        ((size_t)((bh*64 + (t >> 5))*4 + (hd >> 4)))*512
                        + (size_t)((((t >> 3) & 3)*16 + (hd & 15))*8 + (t & 7));
                    ((unsigned short*)Out)[idx] = f2bf(v);
                }
            }
        }
    }
}

// Fused QKV: grid (64, 24); blockIdx.y: 0-7 Q, 8-15 K, 16-23 V
#define QSCALE (0.03125f * 1.44269504088896340736f)   // (1/sqrt(C)) * log2(e)

__global__ __launch_bounds__(256) void gemm_qkv(
    const unsigned short* __restrict__ A,
    const unsigned short* __restrict__ Wq, const unsigned short* __restrict__ Wk,
    const unsigned short* __restrict__ Wv,
    const float* __restrict__ bq, const float* __restrict__ bk,
    const float* __restrict__ bv,
    unsigned short* __restrict__ Qo, unsigned short* __restrict__ Ko,
    unsigned short* __restrict__ Vo)
{
    __shared__ __align__(16) unsigned short As[TM*BK];
    __shared__ __align__(16) unsigned short Bs[TN*BK];
    const int wi = blockIdx.y >> 3;
    const int n_base = (blockIdx.y & 7) * TN;
    const unsigned short* W; const float* bias; void* Out; int mode; float osc;
    if (wi == 0)      { W = Wq; bias = bq; Out = Qo; mode = 1; osc = QSCALE; }
    else if (wi == 1) { W = Wk; bias = bk; Out = Ko; mode = 1; osc = 1.0f; }
    else              { W = Wv; bias = bv; Out = Vo; mode = 2; osc = 1.0f; }
    gemm_core(A, W, bias, Out, As, Bs, blockIdx.x * TM, n_base, NC, NC, mode, osc);
}

__global__ __launch_bounds__(256) void gemm_out(
    const unsigned short* __restrict__ A,
    const unsigned short* __restrict__ W,
    const float* __restrict__ bias,
    float* __restrict__ Out)
{
    __shared__ __align__(16) unsigned short As[TM*BK];
    __shared__ __align__(16) unsigned short Bs[TN*BK];
    gemm_core(A, W, bias, Out, As, Bs, blockIdx.x * TM, blockIdx.y * TN,
              NC, NC, 0, 1.0f);
}

// ---------------- flash attention (causal), fragment-order inputs ----------------
#define LDPP 68   // P stride: 136B row -> 2-way (free) bank pattern

__device__ __forceinline__ void attn_q32(
    const unsigned short* __restrict__ Qf,
    const unsigned short* __restrict__ Kf,
    const unsigned short* __restrict__ Vf,
    unsigned short* __restrict__ Y,
    unsigned short* Pw, int bh, int st, int lane)
{
    const int quad = lane >> 4, l16 = lane & 15;
    const int q0 = st * 32;
    const int b = bh >> 4, h = bh & (NH - 1);

    const size_t qbase = ((size_t)(bh*128 + st*2))*1024 + (size_t)lane*8;
    const bf16x8 qa0 = *(const bf16x8*)&Qf[qbase];
    const bf16x8 qa1 = *(const bf16x8*)&Qf[qbase + 512];
    const bf16x8 qb0 = *(const bf16x8*)&Qf[qbase + 1024];
    const bf16x8 qb1 = *(const bf16x8*)&Qf[qbase + 1536];

    const unsigned short* kp = Kf + (size_t)bh*131072 + (size_t)lane*8;
    const unsigned short* vp = Vf + (size_t)bh*131072 + (size_t)lane*8;

    floatx4 oa[4], ob[4];
    #pragma unroll
    for (int nt = 0; nt < 4; ++nt) {
        oa[nt] = (floatx4){0.f,0.f,0.f,0.f};
        ob[nt] = (floatx4){0.f,0.f,0.f,0.f};
    }
    float la[4] = {0.f,0.f,0.f,0.f}, lb[4] = {0.f,0.f,0.f,0.f};

    const int Ffull = q0 >> 6;   // tiles fully below the diagonal (no masking)

    for (int f = 0; f < Ffull; ++f) {
        const int j0 = f * 64;
        bf16x8 kf[4][2], vf[4][2];
        {
            const unsigned short* kt = kp + (size_t)(j0 >> 4) * 1024;
            #pragma unroll
            for (int ct = 0; ct < 4; ++ct) {
                kf[ct][0] = *(const bf16x8*)&kt[ct*1024];
                kf[ct][1] = *(const bf16x8*)&kt[ct*1024 + 512];
            }
            const unsigned short* vt = vp + (size_t)(j0 >> 5) * 2048;
            #pragma unroll
            for (int nt = 0; nt < 4; ++nt) {
                vf[nt][0] = *(const bf16x8*)&vt[nt*512];
                vf[nt][1] = *(const bf16x8*)&vt[2048 + nt*512];
            }
        }
        // ---- subtile A: no mask needed ----
        {
            floatx4 s[4];
            #pragma unroll
            for (int ct = 0; ct < 4; ++ct) {
                s[ct] = (floatx4){0.f,0.f,0.f,0.f};
                s[ct] = __builtin_amdgcn_mfma_f32_16x16x32_bf16(qa0, kf[ct][0], s[ct], 0,0,0);
                s[ct] = __builtin_amdgcn_mfma_f32_16x16x32_bf16(qa1, kf[ct][1], s[ct], 0,0,0);
            }
            #pragma unroll
            for (int ct = 0; ct < 4; ++ct)
                #pragma unroll
                for (int r = 0; r < 4; ++r) {
                    const float p = __builtin_amdgcn_exp2f(s[ct][r]);
                    la[r] += p;
                    Pw[(quad*4 + r) * LDPP + ct*16 + l16] = f2bf(p);
                }
            const bf16x8 pf0 = *(const bf16x8*)&Pw[l16 * LDPP + quad*8];
            const bf16x8 pf1 = *(const bf16x8*)&Pw[l16 * LDPP + 32 + quad*8];
            #pragma unroll
            for (int nt = 0; nt < 4; ++nt) {
                oa[nt] = __builtin_amdgcn_mfma_f32_16x16x32_bf16(pf0, vf[nt][0], oa[nt], 0,0,0);
                oa[nt] = __builtin_amdgcn_mfma_f32_16x16x32_bf16(pf1, vf[nt][1], oa[nt], 0,0,0);
            }
        }
        // ---- subtile B: no mask needed ----
        {
            floatx4 s[4];
            #pragma unroll
            for (int ct = 0; ct < 4; ++ct) {
                s[ct] = (floatx4){0.f,0.f,0.f,0.f};
                s[ct] = __builtin_amdgcn_mfma_f32_16x16x32_bf16(qb0, kf[ct][0], s[ct], 0,0,0);
                s[ct] = __builtin_amdgcn_mfma_f32_16x16x32_bf16(qb1, kf[ct][1], s[ct], 0,0,0);
            }
            #pragma unroll
            for (int ct = 0; ct < 4; ++ct)
                #pragma unroll
                for (int r = 0; r < 4; ++r) {
                    const float p = __builtin_amdgcn_exp2f(s[ct][r]);
                    lb[r] += p;
                    Pw[(quad*4 + r) * LDPP + ct*16 + l16] = f2bf(p);
                }
            const bf16x8 pf0 = *(const bf16x8*)&Pw[l16 * LDPP + quad*8];
            const bf16x8 pf1 = *(const bf16x8*)&Pw[l16 * LDPP + 32 + quad*8];
            #pragma unroll
            for (int nt = 0; nt < 4; ++nt) {
                ob[nt] = __builtin_amdgcn_mfma_f32_16x16x32_bf16(pf0, vf[nt][0], ob[nt], 0,0,0);
                ob[nt] = __builtin_amdgcn_mfma_f32_16x16x32_bf16(pf1, vf[nt][1], ob[nt], 0,0,0);
            }
        }
    }

    // ---- exactly one diagonal (masked) tile ----
    {
        const int j0 = Ffull * 64;
        bf16x8 kf[4][2], vf[4][2];
        {
            const unsigned short* kt = kp + (size_t)(j0 >> 4) * 1024;
            #pragma unroll
            for (int ct = 0; ct < 4; ++ct) {
                kf[ct][0] = *(const bf16x8*)&kt[ct*1024];
                kf[ct][1] = *(const bf16x8*)&kt[ct*1024 + 512];
            }
            const unsigned short* vt = vp + (size_t)(j0 >> 5) * 2048;
            #pragma unroll
            for (int nt = 0; nt < 4; ++nt) {
                vf[nt][0] = *(const bf16x8*)&vt[nt*512];
                vf[nt][1] = *(const bf16x8*)&vt[2048 + nt*512];
            }
        }
        #pragma unroll
        for (int sub = 0; sub < 2; ++sub) {
            const int row_base = q0 + sub*16;
            const bf16x8 qx0 = sub ? qb0 : qa0;
            const bf16x8 qx1 = sub ? qb1 : qa1;
            float* lx = sub ? lb : la;
            floatx4* ox = sub ? ob : oa;
            floatx4 s[4];
            #pragma unroll
            for (int ct = 0; ct < 4; ++ct) {
                s[ct] = (floatx4){0.f,0.f,0.f,0.f};
                s[ct] = __builtin_amdgcn_mfma_f32_16x16x32_bf16(qx0, kf[ct][0], s[ct], 0,0,0);
                s[ct] = __builtin_amdgcn_mfma_f32_16x16x32_bf16(qx1, kf[ct][1], s[ct], 0,0,0);
            }
            #pragma unroll
            for (int ct = 0; ct < 4; ++ct) {
                const int jlo = j0 + ct*16;
                if (jlo >= row_base + 16) {
                    // fully masked
                    #pragma unroll
                    for (int r = 0; r < 4; ++r)
                        Pw[(quad*4 + r) * LDPP + ct*16 + l16] = 0;
                } else if (jlo + 15 <= row_base) {
                    // fully unmasked
                    #pragma unroll
                    for (int r = 0; r < 4; ++r) {
                        const float p = __builtin_amdgcn_exp2f(s[ct][r]);
                        lx[r] += p;
                        Pw[(quad*4 + r) * LDPP + ct*16 + l16] = f2bf(p);
                    }
                } else {
                    // partial
                    #pragma unroll
                    for (int r = 0; r < 4; ++r) {
                        const int j   = jlo + l16;
                        const int row = row_base + quad*4 + r;
                        const float p = (j <= row) ? __builtin_amdgcn_exp2f(s[ct][r]) : 0.f;
                        lx[r] += p;
                        Pw[(quad*4 + r) * LDPP + ct*16 + l16] = f2bf(p);
                    }
                }
            }
            const bf16x8 pf0 = *(const bf16x8*)&Pw[l16 * LDPP + quad*8];
            const bf16x8 pf1 = *(const bf16x8*)&Pw[l16 * LDPP + 32 + quad*8];
            #pragma unroll
            for (int nt = 0; nt < 4; ++nt) {
                ox[nt] = __builtin_amdgcn_mfma_f32_16x16x32_bf16(pf0, vf[nt][0], ox[nt], 0,0,0);
                ox[nt] = __builtin_amdgcn_mfma_f32_16x16x32_bf16(pf1, vf[nt][1], ox[nt], 0,0,0);
            }
        }
    }

    #pragma unroll
    for (int r = 0; r < 4; ++r) {
        float x = la[r];
        x += __shfl_xor(x, 1, 16); x += __shfl_xor(x, 2, 16);
        x += __shfl_xor(x, 4, 16); x += __shfl_xor(x, 8, 16);
        la[r] = 1.0f / x;
        float y = lb[r];
        y += __shfl_xor(y, 1, 16); y += __shfl_xor(y, 2, 16);
        y += __shfl_xor(y, 4, 16); y += __shfl_xor(y, 8, 16);
        lb[r] = 1.0f / y;
    }
    #pragma unroll
    for (int nt = 0; nt < 4; ++nt) {
        const int col = h * NHD + nt*16 + l16;
        #pragma unroll
        for (int r = 0; r < 4; ++r) {
            const int rowa = q0 + quad*4 + r;
            Y[((size_t)b * NT + rowa) * NC + col] = f2bf(oa[nt][r] * la[r]);
            Y[((size_t)b * NT + rowa + 16) * NC + col] = f2bf(ob[nt][r] * lb[r]);
        }
    }
}

__global__ __launch_bounds__(256) void flash_attn(
    const unsigned short* __restrict__ Qf,
    const unsigned short* __restrict__ Kf,
    const unsigned short* __restrict__ Vf,
    unsigned short* __restrict__ Y)
{
    __shared__ __align__(16) unsigned short Pl[4][16 * LDPP];
    const int tid  = threadIdx.x;
    const int wave = tid >> 6;
    const int lane = tid & 63;
    const int bh = blockIdx.y;
    const int w = blockIdx.x * 4 + wave;   // 0..31
    unsigned short* Pw = &Pl[wave][0];
    attn_q32(Qf, Kf, Vf, Y, Pw, bh, w, lane);
    attn_q32(Qf, Kf, Vf, Y, Pw, bh, 63 - w, lane);
}

// ---------------- launch ----------------
extern "C" void kernel_launch(void* const* d_in, const int* in_sizes, int n_in,
                              void* d_out, int out_size, void* d_ws, size_t ws_size,
                              hipStream_t stream) {
    const float* x  = (const float*)d_in[0];
    const float* Wq = (const float*)d_in[1];
    const float* bq = (const float*)d_in[2];
    const float* Wk = (const float*)d_in[3];
    const float* bk = (const float*)d_in[4];
    const float* Wv = (const float*)d_in[5];
    const float* bv = (const float*)d_in[6];
    const float* Wo = (const float*)d_in[7];
    const float* bo = (const float*)d_in[8];

    char* ws = (char*)d_ws;
    size_t off = 0;
    auto alloc = [&](size_t bytes) -> void* {
        void* p = ws + off;
        off += (bytes + 255) & ~(size_t)255;
        return p;
    };
    unsigned short* xb  = (unsigned short*)alloc((size_t)NM * NC * 2);
    unsigned short* Wqb = (unsigned short*)alloc((size_t)NC * NC * 2);
    unsigned short* Wkb = (unsigned short*)alloc((size_t)NC * NC * 2);
    unsigned short* Wvb = (unsigned short*)alloc((size_t)NC * NC * 2);
    unsigned short* Wob = (unsigned short*)alloc((size_t)NC * NC * 2);
    unsigned short* Qb  = (unsigned short*)alloc((size_t)NM * NC * 2);
    unsigned short* Kb  = (unsigned short*)alloc((size_t)NM * NC * 2);
    unsigned short* Vtb = (unsigned short*)alloc((size_t)NM * NC * 2);
    unsigned short* Yb  = (unsigned short*)alloc((size_t)NM * NC * 2);

    const int nx4 = NM * NC / 4;
    const int nw4 = NC * NC / 4;
    cast_kernel<<<(nx4 + 255)/256, 256, 0, stream>>>(x, xb, nx4);
    cast4_kernel<<<dim3((nw4 + 255)/256, 4), 256, 0, stream>>>(
        Wq, Wk, Wv, Wo, Wqb, Wkb, Wvb, Wob, nw4);

    gemm_qkv<<<dim3(NM / TM, 24), 256, 0, stream>>>(
        xb, Wqb, Wkb, Wvb, bq, bk, bv, Qb, Kb, Vtb);

    flash_attn<<<dim3(8, NB*NH), 256, 0, stream>>>(Qb, Kb, Vtb, Yb);

    gemm_out<<<dim3(NM / TM, NC / TN), 256, 0, stream>>>(Yb, Wob, bo, (float*)d_out);
}

// Round 6
// 312.232 us; speedup vs baseline: 1.0069x; 1.0069x over previous
//
#include <hip/hip_runtime.h>
#include <hip/hip_bf16.h>
#include <stdint.h>

// Problem constants
#define NB 4
#define NT 2048
#define NC 1024
#define NH 16
#define NHD 64
#define NM (NB*NT)   // 8192 rows

typedef __attribute__((ext_vector_type(8))) __bf16 bf16x8;
typedef __attribute__((ext_vector_type(4))) float floatx4;
typedef __attribute__((ext_vector_type(4))) unsigned int uintx4;

#define AS1(p) ((const __attribute__((address_space(1))) void*)(p))
#define AS3(p) ((__attribute__((address_space(3))) void*)(p))

__device__ __forceinline__ unsigned short f2bf(float f) {
    union { float f; unsigned int u; } v; v.f = f;
    unsigned int u = v.u;
    return (unsigned short)((u + 0x7FFFu + ((u >> 16) & 1u)) >> 16);
}

// ---------------- cast fp32 -> bf16 (vectorized x4) ----------------
__global__ void cast_kernel(const float* __restrict__ in,
                            unsigned short* __restrict__ out, int n4) {
    int i = blockIdx.x * blockDim.x + threadIdx.x;
    if (i >= n4) return;
    floatx4 v = ((const floatx4*)in)[i];
    ushort4 o;
    o.x = f2bf(v.x); o.y = f2bf(v.y); o.z = f2bf(v.z); o.w = f2bf(v.w);
    ((ushort4*)out)[i] = o;
}

__global__ void cast4_kernel(const float* __restrict__ w0, const float* __restrict__ w1,
                             const float* __restrict__ w2, const float* __restrict__ w3,
                             unsigned short* __restrict__ o0, unsigned short* __restrict__ o1,
                             unsigned short* __restrict__ o2, unsigned short* __restrict__ o3,
                             int n4) {
    int i = blockIdx.x * blockDim.x + threadIdx.x;
    if (i >= n4) return;
    const float* in; unsigned short* out;
    switch (blockIdx.y) {
        case 0: in = w0; out = o0; break;
        case 1: in = w1; out = o1; break;
        case 2: in = w2; out = o2; break;
        default: in = w3; out = o3; break;
    }
    floatx4 v = ((const floatx4*)in)[i];
    ushort4 o;
    o.x = f2bf(v.x); o.y = f2bf(v.y); o.z = f2bf(v.z); o.w = f2bf(v.w);
    ((ushort4*)out)[i] = o;
}

// ---------------- GEMM core: Out = (A @ W^T + bias) * oscale ----------------
// BK=32 (16KB LDS -> ~30% occupancy; BK=64 regressed: 32KB LDS cut occupancy
// to 22% and MfmaUtil fell — m132 failure mode).
// LDS staged in MFMA fragment order via global_load_lds width=16:
// subtile = 16 rows x 32 k = 512 shorts; lane (quad,l16) stages global
// [row=l16][k=quad*8..+7] at LDS offset lane*8 -> every fragment read is
// &As[subtile*512 + lane*8], a contiguous 1KB wave read, bank-conflict-free
// (round 5: SQ_LDS_BANK_CONFLICT 6.29M -> 0 with this layout).
// mode 0: Out fp32 row-major MxN (final projection)
// mode 1: Out bf16 in MFMA A/B-fragment order for Q/K
// mode 2: Out bf16 in MFMA B-fragment order for V (PV operand)
#define TM 128
#define TN 128
#define BK 32

__device__ __forceinline__ void gemm_core(
    const unsigned short* __restrict__ A,
    const unsigned short* __restrict__ W,
    const float* __restrict__ bias,
    void* __restrict__ Out,
    unsigned short* As, unsigned short* Bs,
    int m_base, int n_base, int N_out, int K, int mode, float oscale)
{
    const int tid  = threadIdx.x;
    const int lane = tid & 63;
    const int wv   = tid >> 6;
    const int quad = lane >> 4;
    const int l16  = lane & 15;
    const int wm = (wv >> 1) * 64;
    const int wn = (wv & 1) * 64;

    floatx4 acc[4][4];
    #pragma unroll
    for (int i = 0; i < 4; ++i)
        #pragma unroll
        for (int j = 0; j < 4; ++j)
            acc[i][j] = (floatx4){0.f, 0.f, 0.f, 0.f};

    const int kTiles = K / BK;

    // staging: lane (quad,l16) -> row l16 (of each 16-row subtile), col quad*8
    const unsigned short* Ab = A + (size_t)(m_base + wv*32 + l16) * K + quad*8;
    const unsigned short* Wb = W + (size_t)(n_base + wv*32 + l16) * K + quad*8;

    for (int kt = 0; kt < kTiles; ++kt) {
        const int k0 = kt * BK;
        __syncthreads();
        #pragma unroll
        for (int i = 0; i < 2; ++i) {           // subtile (16 rows)
            __builtin_amdgcn_global_load_lds(
                AS1(Ab + (size_t)i*16*K + k0),
                AS3(&As[(wv*2 + i)*512]), 16, 0, 0);
            __builtin_amdgcn_global_load_lds(
                AS1(Wb + (size_t)i*16*K + k0),
                AS3(&Bs[(wv*2 + i)*512]), 16, 0, 0);
        }
        __syncthreads();

        bf16x8 af[4], bfr[4];
        #pragma unroll
        for (int mi = 0; mi < 4; ++mi)
            af[mi] = *(const bf16x8*)&As[((wv >> 1)*4 + mi)*512 + lane*8];
        #pragma unroll
        for (int ni = 0; ni < 4; ++ni)
            bfr[ni] = *(const bf16x8*)&Bs[((wv & 1)*4 + ni)*512 + lane*8];

        #pragma unroll
        for (int mi = 0; mi < 4; ++mi)
            #pragma unroll
            for (int ni = 0; ni < 4; ++ni)
                acc[mi][ni] = __builtin_amdgcn_mfma_f32_16x16x32_bf16(
                    af[mi], bfr[ni], acc[mi][ni], 0, 0, 0);
    }

    // epilogue: C/D layout col = lane&15, row = quad*4 + reg
    #pragma unroll
    for (int mi = 0; mi < 4; ++mi) {
        #pragma unroll
        for (int ni = 0; ni < 4; ++ni) {
            const int col = n_base + wn + ni*16 + l16;
            const float bv = bias[col & 1023];
            #pragma unroll
            for (int r = 0; r < 4; ++r) {
                const int row = m_base + wm + mi*16 + quad*4 + r;
                const float v = (acc[mi][ni][r] + bv) * oscale;
                if (mode == 0) {
                    ((float*)Out)[(size_t)row * N_out + col] = v;
                } else if (mode == 1) {
                    const int bb = row >> 11, t = row & (NT - 1);
                    const int h  = (col >> 6) & (NH - 1), d = col & 63;
                    const int bh = bb * NH + h;
                    const size_t idx =
                        ((size_t)((bh*128 + (t >> 4))*2 + (d >> 5)))*512
                        + (size_t)((((d >> 3) & 3)*16 + (t & 15))*8 + (d & 7));
                    ((unsigned short*)Out)[idx] = f2bf(v);
                } else {
                    const int bb = row >> 11, t = row & (NT - 1);
                    const int h  = (col >> 6) & (NH - 1), hd = col & 63;
                    const int bh = bb * NH + h;
                    const size_t idx =
                        ((size_t)((bh*64 + (t >> 5))*4 + (hd >> 4)))*512
                        + (size_t)((((t >> 3) & 3)*16 + (hd & 15))*8 + (t & 7));
                    ((unsigned short*)Out)[idx] = f2bf(v);
                }
            }
        }
    }
}

// Fused QKV: grid (64, 24); blockIdx.y: 0-7 Q, 8-15 K, 16-23 V
#define QSCALE (0.03125f * 1.44269504088896340736f)   // (1/sqrt(C)) * log2(e)

__global__ __launch_bounds__(256) void gemm_qkv(
    const unsigned short* __restrict__ A,
    const unsigned short* __restrict__ Wq, const unsigned short* __restrict__ Wk,
    const unsigned short* __restrict__ Wv,
    const float* __restrict__ bq, const float* __restrict__ bk,
    const float* __restrict__ bv,
    unsigned short* __restrict__ Qo, unsigned short* __restrict__ Ko,
    unsigned short* __restrict__ Vo)
{
    __shared__ __align__(16) unsigned short As[TM*BK];
    __shared__ __align__(16) unsigned short Bs[TN*BK];
    const int wi = blockIdx.y >> 3;
    const int n_base = (blockIdx.y & 7) * TN;
    const unsigned short* W; const float* bias; void* Out; int mode; float osc;
    if (wi == 0)      { W = Wq; bias = bq; Out = Qo; mode = 1; osc = QSCALE; }
    else if (wi == 1) { W = Wk; bias = bk; Out = Ko; mode = 1; osc = 1.0f; }
    else              { W = Wv; bias = bv; Out = Vo; mode = 2; osc = 1.0f; }
    gemm_core(A, W, bias, Out, As, Bs, blockIdx.x * TM, n_base, NC, NC, mode, osc);
}

__global__ __launch_bounds__(256) void gemm_out(
    const unsigned short* __restrict__ A,
    const unsigned short* __restrict__ W,
    const float* __restrict__ bias,
    float* __restrict__ Out)
{
    __shared__ __align__(16) unsigned short As[TM*BK];
    __shared__ __align__(16) unsigned short Bs[TN*BK];
    gemm_core(A, W, bias, Out, As, Bs, blockIdx.x * TM, blockIdx.y * TN,
              NC, NC, 0, 1.0f);
}

// ---------------- flash attention (causal), fragment-order inputs ----------------
#define LDPP 68   // P stride: 136B row -> 2-way (free) bank pattern

__device__ __forceinline__ void attn_q32(
    const unsigned short* __restrict__ Qf,
    const unsigned short* __restrict__ Kf,
    const unsigned short* __restrict__ Vf,
    unsigned short* __restrict__ Y,
    unsigned short* Pw, int bh, int st, int lane)
{
    const int quad = lane >> 4, l16 = lane & 15;
    const int q0 = st * 32;
    const int b = bh >> 4, h = bh & (NH - 1);

    const size_t qbase = ((size_t)(bh*128 + st*2))*1024 + (size_t)lane*8;
    const bf16x8 qa0 = *(const bf16x8*)&Qf[qbase];
    const bf16x8 qa1 = *(const bf16x8*)&Qf[qbase + 512];
    const bf16x8 qb0 = *(const bf16x8*)&Qf[qbase + 1024];
    const bf16x8 qb1 = *(const bf16x8*)&Qf[qbase + 1536];

    const unsigned short* kp = Kf + (size_t)bh*131072 + (size_t)lane*8;
    const unsigned short* vp = Vf + (size_t)bh*131072 + (size_t)lane*8;

    floatx4 oa[4], ob[4];
    #pragma unroll
    for (int nt = 0; nt < 4; ++nt) {
        oa[nt] = (floatx4){0.f,0.f,0.f,0.f};
        ob[nt] = (floatx4){0.f,0.f,0.f,0.f};
    }
    float la[4] = {0.f,0.f,0.f,0.f}, lb[4] = {0.f,0.f,0.f,0.f};

    const int Ffull = q0 >> 6;   // tiles fully below the diagonal (no masking)

    for (int f = 0; f < Ffull; ++f) {
        const int j0 = f * 64;
        bf16x8 kf[4][2], vf[4][2];
        {
            const unsigned short* kt = kp + (size_t)(j0 >> 4) * 1024;
            #pragma unroll
            for (int ct = 0; ct < 4; ++ct) {
                kf[ct][0] = *(const bf16x8*)&kt[ct*1024];
                kf[ct][1] = *(const bf16x8*)&kt[ct*1024 + 512];
            }
            const unsigned short* vt = vp + (size_t)(j0 >> 5) * 2048;
            #pragma unroll
            for (int nt = 0; nt < 4; ++nt) {
                vf[nt][0] = *(const bf16x8*)&vt[nt*512];
                vf[nt][1] = *(const bf16x8*)&vt[2048 + nt*512];
            }
        }
        // ---- subtile A: no mask needed ----
        {
            floatx4 s[4];
            #pragma unroll
            for (int ct = 0; ct < 4; ++ct) {
                s[ct] = (floatx4){0.f,0.f,0.f,0.f};
                s[ct] = __builtin_amdgcn_mfma_f32_16x16x32_bf16(qa0, kf[ct][0], s[ct], 0,0,0);
                s[ct] = __builtin_amdgcn_mfma_f32_16x16x32_bf16(qa1, kf[ct][1], s[ct], 0,0,0);
            }
            #pragma unroll
            for (int ct = 0; ct < 4; ++ct)
                #pragma unroll
                for (int r = 0; r < 4; ++r) {
                    const float p = __builtin_amdgcn_exp2f(s[ct][r]);
                    la[r] += p;
                    Pw[(quad*4 + r) * LDPP + ct*16 + l16] = f2bf(p);
                }
            const bf16x8 pf0 = *(const bf16x8*)&Pw[l16 * LDPP + quad*8];
            const bf16x8 pf1 = *(const bf16x8*)&Pw[l16 * LDPP + 32 + quad*8];
            #pragma unroll
            for (int nt = 0; nt < 4; ++nt) {
                oa[nt] = __builtin_amdgcn_mfma_f32_16x16x32_bf16(pf0, vf[nt][0], oa[nt], 0,0,0);
                oa[nt] = __builtin_amdgcn_mfma_f32_16x16x32_bf16(pf1, vf[nt][1], oa[nt], 0,0,0);
            }
        }
        // ---- subtile B: no mask needed ----
        {
            floatx4 s[4];
            #pragma unroll
            for (int ct = 0; ct < 4; ++ct) {
                s[ct] = (floatx4){0.f,0.f,0.f,0.f};
                s[ct] = __builtin_amdgcn_mfma_f32_16x16x32_bf16(qb0, kf[ct][0], s[ct], 0,0,0);
                s[ct] = __builtin_amdgcn_mfma_f32_16x16x32_bf16(qb1, kf[ct][1], s[ct], 0,0,0);
            }
            #pragma unroll
            for (int ct = 0; ct < 4; ++ct)
                #pragma unroll
                for (int r = 0; r < 4; ++r) {
                    const float p = __builtin_amdgcn_exp2f(s[ct][r]);
                    lb[r] += p;
                    Pw[(quad*4 + r) * LDPP + ct*16 + l16] = f2bf(p);
                }
            const bf16x8 pf0 = *(const bf16x8*)&Pw[l16 * LDPP + quad*8];
            const bf16x8 pf1 = *(const bf16x8*)&Pw[l16 * LDPP + 32 + quad*8];
            #pragma unroll
            for (int nt = 0; nt < 4; ++nt) {
                ob[nt] = __builtin_amdgcn_mfma_f32_16x16x32_bf16(pf0, vf[nt][0], ob[nt], 0,0,0);
                ob[nt] = __builtin_amdgcn_mfma_f32_16x16x32_bf16(pf1, vf[nt][1], ob[nt], 0,0,0);
            }
        }
    }

    // ---- exactly one diagonal (masked) tile ----
    {
        const int j0 = Ffull * 64;
        bf16x8 kf[4][2], vf[4][2];
        {
            const unsigned short* kt = kp + (size_t)(j0 >> 4) * 1024;
            #pragma unroll
            for (int ct = 0; ct < 4; ++ct) {
                kf[ct][0] = *(const bf16x8*)&kt[ct*1024];
                kf[ct][1] = *(const bf16x8*)&kt[ct*1024 + 512];
            }
            const unsigned short* vt = vp + (size_t)(j0 >> 5) * 2048;
            #pragma unroll
            for (int nt = 0; nt < 4; ++nt) {
                vf[nt][0] = *(const bf16x8*)&vt[nt*512];
                vf[nt][1] = *(const bf16x8*)&vt[2048 + nt*512];
            }
        }
        #pragma unroll
        for (int sub = 0; sub < 2; ++sub) {
            const int row_base = q0 + sub*16;
            const bf16x8 qx0 = sub ? qb0 : qa0;
            const bf16x8 qx1 = sub ? qb1 : qa1;
            float* lx = sub ? lb : la;
            floatx4* ox = sub ? ob : oa;
            floatx4 s[4];
            #pragma unroll
            for (int ct = 0; ct < 4; ++ct) {
                s[ct] = (floatx4){0.f,0.f,0.f,0.f};
                s[ct] = __builtin_amdgcn_mfma_f32_16x16x32_bf16(qx0, kf[ct][0], s[ct], 0,0,0);
                s[ct] = __builtin_amdgcn_mfma_f32_16x16x32_bf16(qx1, kf[ct][1], s[ct], 0,0,0);
            }
            #pragma unroll
            for (int ct = 0; ct < 4; ++ct) {
                const int jlo = j0 + ct*16;
                if (jlo >= row_base + 16) {
                    // fully masked
                    #pragma unroll
                    for (int r = 0; r < 4; ++r)
                        Pw[(quad*4 + r) * LDPP + ct*16 + l16] = 0;
                } else if (jlo + 15 <= row_base) {
                    // fully unmasked
                    #pragma unroll
                    for (int r = 0; r < 4; ++r) {
                        const float p = __builtin_amdgcn_exp2f(s[ct][r]);
                        lx[r] += p;
                        Pw[(quad*4 + r) * LDPP + ct*16 + l16] = f2bf(p);
                    }
                } else {
                    // partial
                    #pragma unroll
                    for (int r = 0; r < 4; ++r) {
                        const int j   = jlo + l16;
                        const int row = row_base + quad*4 + r;
                        const float p = (j <= row) ? __builtin_amdgcn_exp2f(s[ct][r]) : 0.f;
                        lx[r] += p;
                        Pw[(quad*4 + r) * LDPP + ct*16 + l16] = f2bf(p);
                    }
                }
            }
            const bf16x8 pf0 = *(const bf16x8*)&Pw[l16 * LDPP + quad*8];
            const bf16x8 pf1 = *(const bf16x8*)&Pw[l16 * LDPP + 32 + quad*8];
            #pragma unroll
            for (int nt = 0; nt < 4; ++nt) {
                ox[nt] = __builtin_amdgcn_mfma_f32_16x16x32_bf16(pf0, vf[nt][0], ox[nt], 0,0,0);
                ox[nt] = __builtin_amdgcn_mfma_f32_16x16x32_bf16(pf1, vf[nt][1], ox[nt], 0,0,0);
            }
        }
    }

    #pragma unroll
    for (int r = 0; r < 4; ++r) {
        float x = la[r];
        x += __shfl_xor(x, 1, 16); x += __shfl_xor(x, 2, 16);
        x += __shfl_xor(x, 4, 16); x += __shfl_xor(x, 8, 16);
        la[r] = 1.0f / x;
        float y = lb[r];
        y += __shfl_xor(y, 1, 16); y += __shfl_xor(y, 2, 16);
        y += __shfl_xor(y, 4, 16); y += __shfl_xor(y, 8, 16);
        lb[r] = 1.0f / y;
    }
    #pragma unroll
    for (int nt = 0; nt < 4; ++nt) {
        const int col = h * NHD + nt*16 + l16;
        #pragma unroll
        for (int r = 0; r < 4; ++r) {
            const int rowa = q0 + quad*4 + r;
            Y[((size_t)b * NT + rowa) * NC + col] = f2bf(oa[nt][r] * la[r]);
            Y[((size_t)b * NT + rowa + 16) * NC + col] = f2bf(ob[nt][r] * lb[r]);
        }
    }
}

__global__ __launch_bounds__(256) void flash_attn(
    const unsigned short* __restrict__ Qf,
    const unsigned short* __restrict__ Kf,
    const unsigned short* __restrict__ Vf,
    unsigned short* __restrict__ Y)
{
    __shared__ __align__(16) unsigned short Pl[4][16 * LDPP];
    const int tid  = threadIdx.x;
    const int wave = tid >> 6;
    const int lane = tid & 63;
    const int bh = blockIdx.y;
    const int w = blockIdx.x * 4 + wave;   // 0..31
    unsigned short* Pw = &Pl[wave][0];
    attn_q32(Qf, Kf, Vf, Y, Pw, bh, w, lane);
    attn_q32(Qf, Kf, Vf, Y, Pw, bh, 63 - w, lane);
}

// ---------------- launch ----------------
extern "C" void kernel_launch(void* const* d_in, const int* in_sizes, int n_in,
                              void* d_out, int out_size, void* d_ws, size_t ws_size,
                              hipStream_t stream) {
    const float* x  = (const float*)d_in[0];
    const float* Wq = (const float*)d_in[1];
    const float* bq = (const float*)d_in[2];
    const float* Wk = (const float*)d_in[3];
    const float* bk = (const float*)d_in[4];
    const float* Wv = (const float*)d_in[5];
    const float* bv = (const float*)d_in[6];
    const float* Wo = (const float*)d_in[7];
    const float* bo = (const float*)d_in[8];

    char* ws = (char*)d_ws;
    size_t off = 0;
    auto alloc = [&](size_t bytes) -> void* {
        void* p = ws + off;
        off += (bytes + 255) & ~(size_t)255;
        return p;
    };
    unsigned short* xb  = (unsigned short*)alloc((size_t)NM * NC * 2);
    unsigned short* Wqb = (unsigned short*)alloc((size_t)NC * NC * 2);
    unsigned short* Wkb = (unsigned short*)alloc((size_t)NC * NC * 2);
    unsigned short* Wvb = (unsigned short*)alloc((size_t)NC * NC * 2);
    unsigned short* Wob = (unsigned short*)alloc((size_t)NC * NC * 2);
    unsigned short* Qb  = (unsigned short*)alloc((size_t)NM * NC * 2);
    unsigned short* Kb  = (unsigned short*)alloc((size_t)NM * NC * 2);
    unsigned short* Vtb = (unsigned short*)alloc((size_t)NM * NC * 2);
    unsigned short* Yb  = (unsigned short*)alloc((size_t)NM * NC * 2);

    const int nx4 = NM * NC / 4;
    const int nw4 = NC * NC / 4;
    cast_kernel<<<(nx4 + 255)/256, 256, 0, stream>>>(x, xb, nx4);
    cast4_kernel<<<dim3((nw4 + 255)/256, 4), 256, 0, stream>>>(
        Wq, Wk, Wv, Wo, Wqb, Wkb, Wvb, Wob, nw4);

    gemm_qkv<<<dim3(NM / TM, 24), 256, 0, stream>>>(
        xb, Wqb, Wkb, Wvb, bq, bk, bv, Qb, Kb, Vtb);

    flash_attn<<<dim3(8, NB*NH), 256, 0, stream>>>(Qb, Kb, Vtb, Yb);

    gemm_out<<<dim3(NM / TM, NC / TN), 256, 0, stream>>>(Yb, Wob, bo, (float*)d_out);
}

// Round 7
// 267.569 us; speedup vs baseline: 1.1749x; 1.1669x over previous
//
#include <hip/hip_runtime.h>
#include <hip/hip_bf16.h>
#include <stdint.h>

// Problem constants
#define NB 4
#define NT 2048
#define NC 1024
#define NH 16
#define NHD 64
#define NM (NB*NT)   // 8192 rows

typedef __attribute__((ext_vector_type(8))) __bf16 bf16x8;
typedef __attribute__((ext_vector_type(4))) float floatx4;
typedef __attribute__((ext_vector_type(4))) unsigned int uintx4;

#define AS1(p) ((const __attribute__((address_space(1))) void*)(p))
#define AS3(p) ((__attribute__((address_space(3))) void*)(p))

__device__ __forceinline__ unsigned short f2bf(float f) {
    union { float f; unsigned int u; } v; v.f = f;
    unsigned int u = v.u;
    return (unsigned short)((u + 0x7FFFu + ((u >> 16) & 1u)) >> 16);
}

// ---------------- cast fp32 -> bf16 (vectorized x4) ----------------
__global__ void cast_kernel(const float* __restrict__ in,
                            unsigned short* __restrict__ out, int n4) {
    int i = blockIdx.x * blockDim.x + threadIdx.x;
    if (i >= n4) return;
    floatx4 v = ((const floatx4*)in)[i];
    ushort4 o;
    o.x = f2bf(v.x); o.y = f2bf(v.y); o.z = f2bf(v.z); o.w = f2bf(v.w);
    ((ushort4*)out)[i] = o;
}

__global__ void cast4_kernel(const float* __restrict__ w0, const float* __restrict__ w1,
                             const float* __restrict__ w2, const float* __restrict__ w3,
                             unsigned short* __restrict__ o0, unsigned short* __restrict__ o1,
                             unsigned short* __restrict__ o2, unsigned short* __restrict__ o3,
                             int n4) {
    int i = blockIdx.x * blockDim.x + threadIdx.x;
    if (i >= n4) return;
    const float* in; unsigned short* out;
    switch (blockIdx.y) {
        case 0: in = w0; out = o0; break;
        case 1: in = w1; out = o1; break;
        case 2: in = w2; out = o2; break;
        default: in = w3; out = o3; break;
    }
    floatx4 v = ((const floatx4*)in)[i];
    ushort4 o;
    o.x = f2bf(v.x); o.y = f2bf(v.y); o.z = f2bf(v.z); o.w = f2bf(v.w);
    ((ushort4*)out)[i] = o;
}

// ---------------- GEMM core: Out = (A @ W^T + bias) * oscale ----------------
// BK=32, 16KB LDS. Staging via global_load_lds width=16 with XOR swizzle:
//   staging lane l (r=l>>2, s=l&3) loads global row r, colgrp g = s^(r&3)^((r>>2)&3)
//   -> 4 consecutive lanes cover one 64B line (round-4 coalescing, fast global)
//   LDS row-major [row][32] with colgrps permuted per row; fragment read at
//   xgrp = quad ^ (l16&3) ^ ((l16>>2)&3) -> banks hit 2-way only (free, m136).
// (round 4: row-major unswizzled = 6.29M conflicts; round 6: fragment-order
//  staging = 0 conflicts but broke global coalescing -> slower. This gets both.)
// mode 0: Out fp32 row-major MxN (final projection)
// mode 1: Out bf16 in MFMA A/B-fragment order for Q/K
// mode 2: Out bf16 in MFMA B-fragment order for V (PV operand)
#define TM 128
#define TN 128
#define BK 32

__device__ __forceinline__ void gemm_core(
    const unsigned short* __restrict__ A,
    const unsigned short* __restrict__ W,
    const float* __restrict__ bias,
    void* __restrict__ Out,
    unsigned short* As, unsigned short* Bs,
    int m_base, int n_base, int N_out, int K, int mode, float oscale)
{
    const int tid  = threadIdx.x;
    const int lane = tid & 63;
    const int wv   = tid >> 6;
    const int quad = lane >> 4;
    const int l16  = lane & 15;
    const int wm = (wv >> 1) * 64;
    const int wn = (wv & 1) * 64;

    floatx4 acc[4][4];
    #pragma unroll
    for (int i = 0; i < 4; ++i)
        #pragma unroll
        for (int j = 0; j < 4; ++j)
            acc[i][j] = (floatx4){0.f, 0.f, 0.f, 0.f};

    const int kTiles = K / BK;

    // staging address: row r = lane>>2 (4 consecutive lanes same row -> one
    // 64B line), global colgrp XOR-swizzled
    const int sR = lane >> 2;
    const int sG = (lane & 3) ^ (sR & 3) ^ ((sR >> 2) & 3);
    const unsigned short* Ab = A + (size_t)(m_base + wv*32 + sR) * K + sG*8;
    const unsigned short* Wb = W + (size_t)(n_base + wv*32 + sR) * K + sG*8;

    // fragment-read swizzled colgrp offset (lane-constant)
    const int xg = ((quad ^ (l16 & 3) ^ ((l16 >> 2) & 3)) & 3) * 8;

    for (int kt = 0; kt < kTiles; ++kt) {
        const int k0 = kt * BK;
        __syncthreads();
        #pragma unroll
        for (int i = 0; i < 2; ++i) {           // subtile (16 rows)
            const int rb = wv*32 + i*16;
            __builtin_amdgcn_global_load_lds(
                AS1(Ab + (size_t)i*16*K + k0), AS3(&As[rb*32]), 16, 0, 0);
            __builtin_amdgcn_global_load_lds(
                AS1(Wb + (size_t)i*16*K + k0), AS3(&Bs[rb*32]), 16, 0, 0);
        }
        __syncthreads();

        bf16x8 af[4], bfr[4];
        #pragma unroll
        for (int mi = 0; mi < 4; ++mi)
            af[mi] = *(const bf16x8*)&As[(wm + mi*16 + l16) * 32 + xg];
        #pragma unroll
        for (int ni = 0; ni < 4; ++ni)
            bfr[ni] = *(const bf16x8*)&Bs[(wn + ni*16 + l16) * 32 + xg];

        #pragma unroll
        for (int mi = 0; mi < 4; ++mi)
            #pragma unroll
            for (int ni = 0; ni < 4; ++ni)
                acc[mi][ni] = __builtin_amdgcn_mfma_f32_16x16x32_bf16(
                    af[mi], bfr[ni], acc[mi][ni], 0, 0, 0);
    }

    // epilogue: C/D layout col = lane&15, row = quad*4 + reg
    #pragma unroll
    for (int mi = 0; mi < 4; ++mi) {
        #pragma unroll
        for (int ni = 0; ni < 4; ++ni) {
            const int col = n_base + wn + ni*16 + l16;
            const float bv = bias[col & 1023];
            #pragma unroll
            for (int r = 0; r < 4; ++r) {
                const int row = m_base + wm + mi*16 + quad*4 + r;
                const float v = (acc[mi][ni][r] + bv) * oscale;
                if (mode == 0) {
                    ((float*)Out)[(size_t)row * N_out + col] = v;
                } else if (mode == 1) {
                    const int bb = row >> 11, t = row & (NT - 1);
                    const int h  = (col >> 6) & (NH - 1), d = col & 63;
                    const int bh = bb * NH + h;
                    const size_t idx =
                        ((size_t)((bh*128 + (t >> 4))*2 + (d >> 5)))*512
                        + (size_t)((((d >> 3) & 3)*16 + (t & 15))*8 + (d & 7));
                    ((unsigned short*)Out)[idx] = f2bf(v);
                } else {
                    const int bb = row >> 11, t = row & (NT - 1);
                    const int h  = (col >> 6) & (NH - 1), hd = col & 63;
                    const int bh = bb * NH + h;
                    const size_t idx =
                        ((size_t)((bh*64 + (t >> 5))*4 + (hd >> 4)))*512
                        + (size_t)((((t >> 3) & 3)*16 + (hd & 15))*8 + (t & 7));
                    ((unsigned short*)Out)[idx] = f2bf(v);
                }
            }
        }
    }
}

// Fused QKV: grid (64, 24); blockIdx.y: 0-7 Q, 8-15 K, 16-23 V
#define QSCALE (0.03125f * 1.44269504088896340736f)   // (1/sqrt(C)) * log2(e)

__global__ __launch_bounds__(256) void gemm_qkv(
    const unsigned short* __restrict__ A,
    const unsigned short* __restrict__ Wq, const unsigned short* __restrict__ Wk,
    const unsigned short* __restrict__ Wv,
    const float* __restrict__ bq, const float* __restrict__ bk,
    const float* __restrict__ bv,
    unsigned short* __restrict__ Qo, unsigned short* __restrict__ Ko,
    unsigned short* __restrict__ Vo)
{
    __shared__ __align__(16) unsigned short As[TM*BK];
    __shared__ __align__(16) unsigned short Bs[TN*BK];
    const int wi = blockIdx.y >> 3;
    const int n_base = (blockIdx.y & 7) * TN;
    const unsigned short* W; const float* bias; void* Out; int mode; float osc;
    if (wi == 0)      { W = Wq; bias = bq; Out = Qo; mode = 1; osc = QSCALE; }
    else if (wi == 1) { W = Wk; bias = bk; Out = Ko; mode = 1; osc = 1.0f; }
    else              { W = Wv; bias = bv; Out = Vo; mode = 2; osc = 1.0f; }
    gemm_core(A, W, bias, Out, As, Bs, blockIdx.x * TM, n_base, NC, NC, mode, osc);
}

__global__ __launch_bounds__(256) void gemm_out(
    const unsigned short* __restrict__ A,
    const unsigned short* __restrict__ W,
    const float* __restrict__ bias,
    float* __restrict__ Out)
{
    __shared__ __align__(16) unsigned short As[TM*BK];
    __shared__ __align__(16) unsigned short Bs[TN*BK];
    gemm_core(A, W, bias, Out, As, Bs, blockIdx.x * TM, blockIdx.y * TN,
              NC, NC, 0, 1.0f);
}

// ---------------- flash attention (causal), fragment-order inputs ----------------
#define LDPP 68   // P stride: 136B row -> 2-way (free) bank pattern

__device__ __forceinline__ void attn_q32(
    const unsigned short* __restrict__ Qf,
    const unsigned short* __restrict__ Kf,
    const unsigned short* __restrict__ Vf,
    unsigned short* __restrict__ Y,
    unsigned short* Pw, int bh, int st, int lane)
{
    const int quad = lane >> 4, l16 = lane & 15;
    const int q0 = st * 32;
    const int b = bh >> 4, h = bh & (NH - 1);

    const size_t qbase = ((size_t)(bh*128 + st*2))*1024 + (size_t)lane*8;
    const bf16x8 qa0 = *(const bf16x8*)&Qf[qbase];
    const bf16x8 qa1 = *(const bf16x8*)&Qf[qbase + 512];
    const bf16x8 qb0 = *(const bf16x8*)&Qf[qbase + 1024];
    const bf16x8 qb1 = *(const bf16x8*)&Qf[qbase + 1536];

    const unsigned short* kp = Kf + (size_t)bh*131072 + (size_t)lane*8;
    const unsigned short* vp = Vf + (size_t)bh*131072 + (size_t)lane*8;

    floatx4 oa[4], ob[4];
    #pragma unroll
    for (int nt = 0; nt < 4; ++nt) {
        oa[nt] = (floatx4){0.f,0.f,0.f,0.f};
        ob[nt] = (floatx4){0.f,0.f,0.f,0.f};
    }
    float la[4] = {0.f,0.f,0.f,0.f}, lb[4] = {0.f,0.f,0.f,0.f};

    const int Ffull = q0 >> 6;   // tiles fully below the diagonal (no masking)

    for (int f = 0; f < Ffull; ++f) {
        const int j0 = f * 64;
        bf16x8 kf[4][2], vf[4][2];
        {
            const unsigned short* kt = kp + (size_t)(j0 >> 4) * 1024;
            #pragma unroll
            for (int ct = 0; ct < 4; ++ct) {
                kf[ct][0] = *(const bf16x8*)&kt[ct*1024];
                kf[ct][1] = *(const bf16x8*)&kt[ct*1024 + 512];
            }
            const unsigned short* vt = vp + (size_t)(j0 >> 5) * 2048;
            #pragma unroll
            for (int nt = 0; nt < 4; ++nt) {
                vf[nt][0] = *(const bf16x8*)&vt[nt*512];
                vf[nt][1] = *(const bf16x8*)&vt[2048 + nt*512];
            }
        }
        // ---- subtile A: no mask needed ----
        {
            floatx4 s[4];
            #pragma unroll
            for (int ct = 0; ct < 4; ++ct) {
                s[ct] = (floatx4){0.f,0.f,0.f,0.f};
                s[ct] = __builtin_amdgcn_mfma_f32_16x16x32_bf16(qa0, kf[ct][0], s[ct], 0,0,0);
                s[ct] = __builtin_amdgcn_mfma_f32_16x16x32_bf16(qa1, kf[ct][1], s[ct], 0,0,0);
            }
            #pragma unroll
            for (int ct = 0; ct < 4; ++ct)
                #pragma unroll
                for (int r = 0; r < 4; ++r) {
                    const float p = __builtin_amdgcn_exp2f(s[ct][r]);
                    la[r] += p;
                    Pw[(quad*4 + r) * LDPP + ct*16 + l16] = f2bf(p);
                }
            const bf16x8 pf0 = *(const bf16x8*)&Pw[l16 * LDPP + quad*8];
            const bf16x8 pf1 = *(const bf16x8*)&Pw[l16 * LDPP + 32 + quad*8];
            #pragma unroll
            for (int nt = 0; nt < 4; ++nt) {
                oa[nt] = __builtin_amdgcn_mfma_f32_16x16x32_bf16(pf0, vf[nt][0], oa[nt], 0,0,0);
                oa[nt] = __builtin_amdgcn_mfma_f32_16x16x32_bf16(pf1, vf[nt][1], oa[nt], 0,0,0);
            }
        }
        // ---- subtile B: no mask needed ----
        {
            floatx4 s[4];
            #pragma unroll
            for (int ct = 0; ct < 4; ++ct) {
                s[ct] = (floatx4){0.f,0.f,0.f,0.f};
                s[ct] = __builtin_amdgcn_mfma_f32_16x16x32_bf16(qb0, kf[ct][0], s[ct], 0,0,0);
                s[ct] = __builtin_amdgcn_mfma_f32_16x16x32_bf16(qb1, kf[ct][1], s[ct], 0,0,0);
            }
            #pragma unroll
            for (int ct = 0; ct < 4; ++ct)
                #pragma unroll
                for (int r = 0; r < 4; ++r) {
                    const float p = __builtin_amdgcn_exp2f(s[ct][r]);
                    lb[r] += p;
                    Pw[(quad*4 + r) * LDPP + ct*16 + l16] = f2bf(p);
                }
            const bf16x8 pf0 = *(const bf16x8*)&Pw[l16 * LDPP + quad*8];
            const bf16x8 pf1 = *(const bf16x8*)&Pw[l16 * LDPP + 32 + quad*8];
            #pragma unroll
            for (int nt = 0; nt < 4; ++nt) {
                ob[nt] = __builtin_amdgcn_mfma_f32_16x16x32_bf16(pf0, vf[nt][0], ob[nt], 0,0,0);
                ob[nt] = __builtin_amdgcn_mfma_f32_16x16x32_bf16(pf1, vf[nt][1], ob[nt], 0,0,0);
            }
        }
    }

    // ---- exactly one diagonal (masked) tile ----
    {
        const int j0 = Ffull * 64;
        bf16x8 kf[4][2], vf[4][2];
        {
            const unsigned short* kt = kp + (size_t)(j0 >> 4) * 1024;
            #pragma unroll
            for (int ct = 0; ct < 4; ++ct) {
                kf[ct][0] = *(const bf16x8*)&kt[ct*1024];
                kf[ct][1] = *(const bf16x8*)&kt[ct*1024 + 512];
            }
            const unsigned short* vt = vp + (size_t)(j0 >> 5) * 2048;
            #pragma unroll
            for (int nt = 0; nt < 4; ++nt) {
                vf[nt][0] = *(const bf16x8*)&vt[nt*512];
                vf[nt][1] = *(const bf16x8*)&vt[2048 + nt*512];
            }
        }
        #pragma unroll
        for (int sub = 0; sub < 2; ++sub) {
            const int row_base = q0 + sub*16;
            const bf16x8 qx0 = sub ? qb0 : qa0;
            const bf16x8 qx1 = sub ? qb1 : qa1;
            float* lx = sub ? lb : la;
            floatx4* ox = sub ? ob : oa;
            floatx4 s[4];
            #pragma unroll
            for (int ct = 0; ct < 4; ++ct) {
                s[ct] = (floatx4){0.f,0.f,0.f,0.f};
                s[ct] = __builtin_amdgcn_mfma_f32_16x16x32_bf16(qx0, kf[ct][0], s[ct], 0,0,0);
                s[ct] = __builtin_amdgcn_mfma_f32_16x16x32_bf16(qx1, kf[ct][1], s[ct], 0,0,0);
            }
            #pragma unroll
            for (int ct = 0; ct < 4; ++ct) {
                const int jlo = j0 + ct*16;
                if (jlo >= row_base + 16) {
                    // fully masked
                    #pragma unroll
                    for (int r = 0; r < 4; ++r)
                        Pw[(quad*4 + r) * LDPP + ct*16 + l16] = 0;
                } else if (jlo + 15 <= row_base) {
                    // fully unmasked
                    #pragma unroll
                    for (int r = 0; r < 4; ++r) {
                        const float p = __builtin_amdgcn_exp2f(s[ct][r]);
                        lx[r] += p;
                        Pw[(quad*4 + r) * LDPP + ct*16 + l16] = f2bf(p);
                    }
                } else {
                    // partial
                    #pragma unroll
                    for (int r = 0; r < 4; ++r) {
                        const int j   = jlo + l16;
                        const int row = row_base + quad*4 + r;
                        const float p = (j <= row) ? __builtin_amdgcn_exp2f(s[ct][r]) : 0.f;
                        lx[r] += p;
                        Pw[(quad*4 + r) * LDPP + ct*16 + l16] = f2bf(p);
                    }
                }
            }
            const bf16x8 pf0 = *(const bf16x8*)&Pw[l16 * LDPP + quad*8];
            const bf16x8 pf1 = *(const bf16x8*)&Pw[l16 * LDPP + 32 + quad*8];
            #pragma unroll
            for (int nt = 0; nt < 4; ++nt) {
                ox[nt] = __builtin_amdgcn_mfma_f32_16x16x32_bf16(pf0, vf[nt][0], ox[nt], 0,0,0);
                ox[nt] = __builtin_amdgcn_mfma_f32_16x16x32_bf16(pf1, vf[nt][1], ox[nt], 0,0,0);
            }
        }
    }

    #pragma unroll
    for (int r = 0; r < 4; ++r) {
        float x = la[r];
        x += __shfl_xor(x, 1, 16); x += __shfl_xor(x, 2, 16);
        x += __shfl_xor(x, 4, 16); x += __shfl_xor(x, 8, 16);
        la[r] = 1.0f / x;
        float y = lb[r];
        y += __shfl_xor(y, 1, 16); y += __shfl_xor(y, 2, 16);
        y += __shfl_xor(y, 4, 16); y += __shfl_xor(y, 8, 16);
        lb[r] = 1.0f / y;
    }
    #pragma unroll
    for (int nt = 0; nt < 4; ++nt) {
        const int col = h * NHD + nt*16 + l16;
        #pragma unroll
        for (int r = 0; r < 4; ++r) {
            const int rowa = q0 + quad*4 + r;
            Y[((size_t)b * NT + rowa) * NC + col] = f2bf(oa[nt][r] * la[r]);
            Y[((size_t)b * NT + rowa + 16) * NC + col] = f2bf(ob[nt][r] * lb[r]);
        }
    }
}

__global__ __launch_bounds__(256) void flash_attn(
    const unsigned short* __restrict__ Qf,
    const unsigned short* __restrict__ Kf,
    const unsigned short* __restrict__ Vf,
    unsigned short* __restrict__ Y)
{
    __shared__ __align__(16) unsigned short Pl[4][16 * LDPP];
    const int tid  = threadIdx.x;
    const int wave = tid >> 6;
    const int lane = tid & 63;
    const int bh = blockIdx.y;
    const int w = blockIdx.x * 4 + wave;   // 0..31
    unsigned short* Pw = &Pl[wave][0];
    attn_q32(Qf, Kf, Vf, Y, Pw, bh, w, lane);
    attn_q32(Qf, Kf, Vf, Y, Pw, bh, 63 - w, lane);
}

// ---------------- launch ----------------
extern "C" void kernel_launch(void* const* d_in, const int* in_sizes, int n_in,
                              void* d_out, int out_size, void* d_ws, size_t ws_size,
                              hipStream_t stream) {
    const float* x  = (const float*)d_in[0];
    const float* Wq = (const float*)d_in[1];
    const float* bq = (const float*)d_in[2];
    const float* Wk = (const float*)d_in[3];
    const float* bk = (const float*)d_in[4];
    const float* Wv = (const float*)d_in[5];
    const float* bv = (const float*)d_in[6];
    const float* Wo = (const float*)d_in[7];
    const float* bo = (const float*)d_in[8];

    char* ws = (char*)d_ws;
    size_t off = 0;
    auto alloc = [&](size_t bytes) -> void* {
        void* p = ws + off;
        off += (bytes + 255) & ~(size_t)255;
        return p;
    };
    unsigned short* xb  = (unsigned short*)alloc((size_t)NM * NC * 2);
    unsigned short* Wqb = (unsigned short*)alloc((size_t)NC * NC * 2);
    unsigned short* Wkb = (unsigned short*)alloc((size_t)NC * NC * 2);
    unsigned short* Wvb = (unsigned short*)alloc((size_t)NC * NC * 2);
    unsigned short* Wob = (unsigned short*)alloc((size_t)NC * NC * 2);
    unsigned short* Qb  = (unsigned short*)alloc((size_t)NM * NC * 2);
    unsigned short* Kb  = (unsigned short*)alloc((size_t)NM * NC * 2);
    unsigned short* Vtb = (unsigned short*)alloc((size_t)NM * NC * 2);
    unsigned short* Yb  = (unsigned short*)alloc((size_t)NM * NC * 2);

    const int nx4 = NM * NC / 4;
    const int nw4 = NC * NC / 4;
    cast_kernel<<<(nx4 + 255)/256, 256, 0, stream>>>(x, xb, nx4);
    cast4_kernel<<<dim3((nw4 + 255)/256, 4), 256, 0, stream>>>(
        Wq, Wk, Wv, Wo, Wqb, Wkb, Wvb, Wob, nw4);

    gemm_qkv<<<dim3(NM / TM, 24), 256, 0, stream>>>(
        xb, Wqb, Wkb, Wvb, bq, bk, bv, Qb, Kb, Vtb);

    flash_attn<<<dim3(8, NB*NH), 256, 0, stream>>>(Qb, Kb, Vtb, Yb);

    gemm_out<<<dim3(NM / TM, NC / TN), 256, 0, stream>>>(Yb, Wob, bo, (float*)d_out);
}

// Round 8
// 254.716 us; speedup vs baseline: 1.2342x; 1.0505x over previous
//
#include <hip/hip_runtime.h>
#include <hip/hip_bf16.h>
#include <stdint.h>

// Problem constants
#define NB 4
#define NT 2048
#define NC 1024
#define NH 16
#define NHD 64
#define NM (NB*NT)   // 8192 rows

typedef __attribute__((ext_vector_type(8))) __bf16 bf16x8;
typedef __attribute__((ext_vector_type(4))) float floatx4;
typedef __attribute__((ext_vector_type(8))) unsigned short ushortx8;

#define AS1(p) ((const __attribute__((address_space(1))) void*)(p))
#define AS3(p) ((__attribute__((address_space(3))) void*)(p))

__device__ __forceinline__ unsigned short f2bf(float f) {
    union { float f; unsigned int u; } v; v.f = f;
    unsigned int u = v.u;
    return (unsigned short)((u + 0x7FFFu + ((u >> 16) & 1u)) >> 16);
}

// ===== fragment-tiled layout (for all GEMM operands) =====
// matrix (rows x 1024 cols) stored as 16x32 tiles of 512 shorts:
//   tile (R=row/16, C=col/32) at offset (R*32 + C)*512
//   element (r=row&15, c=col&31) at ((c>>3)*16 + r)*8 + (c&7)
// -> GEMM staging & LDS fragment reads are both contiguous base+lane*16B
//    (r4/r7: row-major LDS b128 reads = +4cyc/instr conflicts regardless of
//     swizzle; r6: contiguous LDS reads = 0 conflicts but scattered global.
//     Fragment-tiled global gets both sides contiguous.)

// ---------------- cast fp32 -> bf16, fragment-tiled (1 tile per wave) -------
__global__ void cast_x_tiled(const float* __restrict__ in,
                             unsigned short* __restrict__ out, int ntiles) {
    const int wid  = (blockIdx.x * blockDim.x + threadIdx.x) >> 6;
    const int lane = threadIdx.x & 63;
    if (wid >= ntiles) return;
    const int R = wid >> 5, C = wid & 31;
    const float* src = in + ((size_t)(R*16 + (lane >> 2)))*1024 + C*32 + (lane & 3)*8;
    const floatx4 v0 = *(const floatx4*)src;
    const floatx4 v1 = *(const floatx4*)(src + 4);
    ushortx8 o;
    o[0] = f2bf(v0[0]); o[1] = f2bf(v0[1]); o[2] = f2bf(v0[2]); o[3] = f2bf(v0[3]);
    o[4] = f2bf(v1[0]); o[5] = f2bf(v1[1]); o[6] = f2bf(v1[2]); o[7] = f2bf(v1[3]);
    *(ushortx8*)&out[(size_t)wid*512 + (((lane & 3)*16 + (lane >> 2)))*8] = o;
}

__global__ void cast4_tiled(const float* __restrict__ w0, const float* __restrict__ w1,
                            const float* __restrict__ w2, const float* __restrict__ w3,
                            unsigned short* __restrict__ o0, unsigned short* __restrict__ o1,
                            unsigned short* __restrict__ o2, unsigned short* __restrict__ o3,
                            int ntiles) {
    const int wid  = (blockIdx.x * blockDim.x + threadIdx.x) >> 6;
    const int lane = threadIdx.x & 63;
    if (wid >= ntiles) return;
    const float* in; unsigned short* out;
    switch (blockIdx.y) {
        case 0: in = w0; out = o0; break;
        case 1: in = w1; out = o1; break;
        case 2: in = w2; out = o2; break;
        default: in = w3; out = o3; break;
    }
    const int R = wid >> 5, C = wid & 31;
    const float* src = in + ((size_t)(R*16 + (lane >> 2)))*1024 + C*32 + (lane & 3)*8;
    const floatx4 v0 = *(const floatx4*)src;
    const floatx4 v1 = *(const floatx4*)(src + 4);
    ushortx8 o;
    o[0] = f2bf(v0[0]); o[1] = f2bf(v0[1]); o[2] = f2bf(v0[2]); o[3] = f2bf(v0[3]);
    o[4] = f2bf(v1[0]); o[5] = f2bf(v1[1]); o[6] = f2bf(v1[2]); o[7] = f2bf(v1[3]);
    *(ushortx8*)&out[(size_t)wid*512 + (((lane & 3)*16 + (lane >> 2)))*8] = o;
}

// ---------------- GEMM core: Out = (A @ W^T + bias) * oscale ----------------
// A, W fragment-tiled (see above), K=1024. BK=32, 16KB LDS.
// mode 0: Out fp32 row-major MxN (final projection)
// mode 1: Out bf16 in MFMA A/B-fragment order for Q/K
// mode 2: Out bf16 in MFMA B-fragment order for V (PV operand)
#define TM 128
#define TN 128
#define BK 32

__device__ __forceinline__ void gemm_core(
    const unsigned short* __restrict__ A,
    const unsigned short* __restrict__ W,
    const float* __restrict__ bias,
    void* __restrict__ Out,
    unsigned short* As, unsigned short* Bs,
    int m_base, int n_base, int N_out, int K, int mode, float oscale)
{
    const int tid  = threadIdx.x;
    const int lane = tid & 63;
    const int wv   = tid >> 6;
    const int quad = lane >> 4;
    const int l16  = lane & 15;
    const int wm = (wv >> 1) * 64;
    const int wn = (wv & 1) * 64;

    floatx4 acc[4][4];
    #pragma unroll
    for (int i = 0; i < 4; ++i)
        #pragma unroll
        for (int j = 0; j < 4; ++j)
            acc[i][j] = (floatx4){0.f, 0.f, 0.f, 0.f};

    const int kTiles = K / BK;            // K-tiles = col-tiles (C index)
    const int kct = K >> 5;               // col-tiles per row-block

    // staging: contiguous 1KB per issue (tile base + lane*16B)
    const unsigned short* At = A + ((size_t)((m_base >> 4) + wv*2) * kct) * 512 + (size_t)lane*8;
    const unsigned short* Wt = W + ((size_t)((n_base >> 4) + wv*2) * kct) * 512 + (size_t)lane*8;
    const size_t rstride = (size_t)kct * 512;   // one row-block (16 rows)

    for (int kt = 0; kt < kTiles; ++kt) {
        __syncthreads();
        #pragma unroll
        for (int i = 0; i < 2; ++i) {
            __builtin_amdgcn_global_load_lds(
                AS1(At + (size_t)kt*512 + i*rstride),
                AS3(&As[(wv*2 + i)*512]), 16, 0, 0);
            __builtin_amdgcn_global_load_lds(
                AS1(Wt + (size_t)kt*512 + i*rstride),
                AS3(&Bs[(wv*2 + i)*512]), 16, 0, 0);
        }
        __syncthreads();

        bf16x8 af[4], bfr[4];
        #pragma unroll
        for (int mi = 0; mi < 4; ++mi)
            af[mi] = *(const bf16x8*)&As[((wv >> 1)*4 + mi)*512 + lane*8];
        #pragma unroll
        for (int ni = 0; ni < 4; ++ni)
            bfr[ni] = *(const bf16x8*)&Bs[((wv & 1)*4 + ni)*512 + lane*8];

        #pragma unroll
        for (int mi = 0; mi < 4; ++mi)
            #pragma unroll
            for (int ni = 0; ni < 4; ++ni)
                acc[mi][ni] = __builtin_amdgcn_mfma_f32_16x16x32_bf16(
                    af[mi], bfr[ni], acc[mi][ni], 0, 0, 0);
    }

    // epilogue: C/D layout col = lane&15, row = quad*4 + reg
    #pragma unroll
    for (int mi = 0; mi < 4; ++mi) {
        #pragma unroll
        for (int ni = 0; ni < 4; ++ni) {
            const int col = n_base + wn + ni*16 + l16;
            const float bv = bias[col & 1023];
            #pragma unroll
            for (int r = 0; r < 4; ++r) {
                const int row = m_base + wm + mi*16 + quad*4 + r;
                const float v = (acc[mi][ni][r] + bv) * oscale;
                if (mode == 0) {
                    ((float*)Out)[(size_t)row * N_out + col] = v;
                } else if (mode == 1) {
                    const int bb = row >> 11, t = row & (NT - 1);
                    const int h  = (col >> 6) & (NH - 1), d = col & 63;
                    const int bh = bb * NH + h;
                    const size_t idx =
                        ((size_t)((bh*128 + (t >> 4))*2 + (d >> 5)))*512
                        + (size_t)((((d >> 3) & 3)*16 + (t & 15))*8 + (d & 7));
                    ((unsigned short*)Out)[idx] = f2bf(v);
                } else {
                    const int bb = row >> 11, t = row & (NT - 1);
                    const int h  = (col >> 6) & (NH - 1), hd = col & 63;
                    const int bh = bb * NH + h;
                    const size_t idx =
                        ((size_t)((bh*64 + (t >> 5))*4 + (hd >> 4)))*512
                        + (size_t)((((t >> 3) & 3)*16 + (hd & 15))*8 + (t & 7));
                    ((unsigned short*)Out)[idx] = f2bf(v);
                }
            }
        }
    }
}

// Fused QKV: grid (64, 24); blockIdx.y: 0-7 Q, 8-15 K, 16-23 V
#define QSCALE (0.03125f * 1.44269504088896340736f)   // (1/sqrt(C)) * log2(e)

__global__ __launch_bounds__(256) void gemm_qkv(
    const unsigned short* __restrict__ A,
    const unsigned short* __restrict__ Wq, const unsigned short* __restrict__ Wk,
    const unsigned short* __restrict__ Wv,
    const float* __restrict__ bq, const float* __restrict__ bk,
    const float* __restrict__ bv,
    unsigned short* __restrict__ Qo, unsigned short* __restrict__ Ko,
    unsigned short* __restrict__ Vo)
{
    __shared__ __align__(16) unsigned short As[TM*BK];
    __shared__ __align__(16) unsigned short Bs[TN*BK];
    const int wi = blockIdx.y >> 3;
    const int n_base = (blockIdx.y & 7) * TN;
    const unsigned short* W; const float* bias; void* Out; int mode; float osc;
    if (wi == 0)      { W = Wq; bias = bq; Out = Qo; mode = 1; osc = QSCALE; }
    else if (wi == 1) { W = Wk; bias = bk; Out = Ko; mode = 1; osc = 1.0f; }
    else              { W = Wv; bias = bv; Out = Vo; mode = 2; osc = 1.0f; }
    gemm_core(A, W, bias, Out, As, Bs, blockIdx.x * TM, n_base, NC, NC, mode, osc);
}

__global__ __launch_bounds__(256) void gemm_out(
    const unsigned short* __restrict__ A,
    const unsigned short* __restrict__ W,
    const float* __restrict__ bias,
    float* __restrict__ Out)
{
    __shared__ __align__(16) unsigned short As[TM*BK];
    __shared__ __align__(16) unsigned short Bs[TN*BK];
    gemm_core(A, W, bias, Out, As, Bs, blockIdx.x * TM, blockIdx.y * TN,
              NC, NC, 0, 1.0f);
}

// ---------------- flash attention (causal), fragment-order inputs ----------------
#define LDPP 68   // P stride: 136B row -> 2-way (free) bank pattern

__device__ __forceinline__ void attn_q32(
    const unsigned short* __restrict__ Qf,
    const unsigned short* __restrict__ Kf,
    const unsigned short* __restrict__ Vf,
    unsigned short* __restrict__ Y,      // fragment-tiled (B*T x 1024)
    unsigned short* Pw, int bh, int st, int lane)
{
    const int quad = lane >> 4, l16 = lane & 15;
    const int q0 = st * 32;
    const int b = bh >> 4, h = bh & (NH - 1);

    const size_t qbase = ((size_t)(bh*128 + st*2))*1024 + (size_t)lane*8;
    const bf16x8 qa0 = *(const bf16x8*)&Qf[qbase];
    const bf16x8 qa1 = *(const bf16x8*)&Qf[qbase + 512];
    const bf16x8 qb0 = *(const bf16x8*)&Qf[qbase + 1024];
    const bf16x8 qb1 = *(const bf16x8*)&Qf[qbase + 1536];

    const unsigned short* kp = Kf + (size_t)bh*131072 + (size_t)lane*8;
    const unsigned short* vp = Vf + (size_t)bh*131072 + (size_t)lane*8;

    floatx4 oa[4], ob[4];
    #pragma unroll
    for (int nt = 0; nt < 4; ++nt) {
        oa[nt] = (floatx4){0.f,0.f,0.f,0.f};
        ob[nt] = (floatx4){0.f,0.f,0.f,0.f};
    }
    float la[4] = {0.f,0.f,0.f,0.f}, lb[4] = {0.f,0.f,0.f,0.f};

    const int Ffull = q0 >> 6;   // tiles fully below the diagonal (no masking)

    for (int f = 0; f < Ffull; ++f) {
        const int j0 = f * 64;
        bf16x8 kf[4][2], vf[4][2];
        {
            const unsigned short* kt = kp + (size_t)(j0 >> 4) * 1024;
            #pragma unroll
            for (int ct = 0; ct < 4; ++ct) {
                kf[ct][0] = *(const bf16x8*)&kt[ct*1024];
                kf[ct][1] = *(const bf16x8*)&kt[ct*1024 + 512];
            }
            const unsigned short* vt = vp + (size_t)(j0 >> 5) * 2048;
            #pragma unroll
            for (int nt = 0; nt < 4; ++nt) {
                vf[nt][0] = *(const bf16x8*)&vt[nt*512];
                vf[nt][1] = *(const bf16x8*)&vt[2048 + nt*512];
            }
        }
        // ---- subtile A: no mask needed ----
        {
            floatx4 s[4];
            #pragma unroll
            for (int ct = 0; ct < 4; ++ct) {
                s[ct] = (floatx4){0.f,0.f,0.f,0.f};
                s[ct] = __builtin_amdgcn_mfma_f32_16x16x32_bf16(qa0, kf[ct][0], s[ct], 0,0,0);
                s[ct] = __builtin_amdgcn_mfma_f32_16x16x32_bf16(qa1, kf[ct][1], s[ct], 0,0,0);
            }
            #pragma unroll
            for (int ct = 0; ct < 4; ++ct)
                #pragma unroll
                for (int r = 0; r < 4; ++r) {
                    const float p = __builtin_amdgcn_exp2f(s[ct][r]);
                    la[r] += p;
                    Pw[(quad*4 + r) * LDPP + ct*16 + l16] = f2bf(p);
                }
            const bf16x8 pf0 = *(const bf16x8*)&Pw[l16 * LDPP + quad*8];
            const bf16x8 pf1 = *(const bf16x8*)&Pw[l16 * LDPP + 32 + quad*8];
            #pragma unroll
            for (int nt = 0; nt < 4; ++nt) {
                oa[nt] = __builtin_amdgcn_mfma_f32_16x16x32_bf16(pf0, vf[nt][0], oa[nt], 0,0,0);
                oa[nt] = __builtin_amdgcn_mfma_f32_16x16x32_bf16(pf1, vf[nt][1], oa[nt], 0,0,0);
            }
        }
        // ---- subtile B: no mask needed ----
        {
            floatx4 s[4];
            #pragma unroll
            for (int ct = 0; ct < 4; ++ct) {
                s[ct] = (floatx4){0.f,0.f,0.f,0.f};
                s[ct] = __builtin_amdgcn_mfma_f32_16x16x32_bf16(qb0, kf[ct][0], s[ct], 0,0,0);
                s[ct] = __builtin_amdgcn_mfma_f32_16x16x32_bf16(qb1, kf[ct][1], s[ct], 0,0,0);
            }
            #pragma unroll
            for (int ct = 0; ct < 4; ++ct)
                #pragma unroll
                for (int r = 0; r < 4; ++r) {
                    const float p = __builtin_amdgcn_exp2f(s[ct][r]);
                    lb[r] += p;
                    Pw[(quad*4 + r) * LDPP + ct*16 + l16] = f2bf(p);
                }
            const bf16x8 pf0 = *(const bf16x8*)&Pw[l16 * LDPP + quad*8];
            const bf16x8 pf1 = *(const bf16x8*)&Pw[l16 * LDPP + 32 + quad*8];
            #pragma unroll
            for (int nt = 0; nt < 4; ++nt) {
                ob[nt] = __builtin_amdgcn_mfma_f32_16x16x32_bf16(pf0, vf[nt][0], ob[nt], 0,0,0);
                ob[nt] = __builtin_amdgcn_mfma_f32_16x16x32_bf16(pf1, vf[nt][1], ob[nt], 0,0,0);
            }
        }
    }

    // ---- exactly one diagonal (masked) tile ----
    {
        const int j0 = Ffull * 64;
        bf16x8 kf[4][2], vf[4][2];
        {
            const unsigned short* kt = kp + (size_t)(j0 >> 4) * 1024;
            #pragma unroll
            for (int ct = 0; ct < 4; ++ct) {
                kf[ct][0] = *(const bf16x8*)&kt[ct*1024];
                kf[ct][1] = *(const bf16x8*)&kt[ct*1024 + 512];
            }
            const unsigned short* vt = vp + (size_t)(j0 >> 5) * 2048;
            #pragma unroll
            for (int nt = 0; nt < 4; ++nt) {
                vf[nt][0] = *(const bf16x8*)&vt[nt*512];
                vf[nt][1] = *(const bf16x8*)&vt[2048 + nt*512];
            }
        }
        #pragma unroll
        for (int sub = 0; sub < 2; ++sub) {
            const int row_base = q0 + sub*16;
            const bf16x8 qx0 = sub ? qb0 : qa0;
            const bf16x8 qx1 = sub ? qb1 : qa1;
            float* lx = sub ? lb : la;
            floatx4* ox = sub ? ob : oa;
            floatx4 s[4];
            #pragma unroll
            for (int ct = 0; ct < 4; ++ct) {
                s[ct] = (floatx4){0.f,0.f,0.f,0.f};
                s[ct] = __builtin_amdgcn_mfma_f32_16x16x32_bf16(qx0, kf[ct][0], s[ct], 0,0,0);
                s[ct] = __builtin_amdgcn_mfma_f32_16x16x32_bf16(qx1, kf[ct][1], s[ct], 0,0,0);
            }
            #pragma unroll
            for (int ct = 0; ct < 4; ++ct) {
                const int jlo = j0 + ct*16;
                if (jlo >= row_base + 16) {
                    #pragma unroll
                    for (int r = 0; r < 4; ++r)
                        Pw[(quad*4 + r) * LDPP + ct*16 + l16] = 0;
                } else if (jlo + 15 <= row_base) {
                    #pragma unroll
                    for (int r = 0; r < 4; ++r) {
                        const float p = __builtin_amdgcn_exp2f(s[ct][r]);
                        lx[r] += p;
                        Pw[(quad*4 + r) * LDPP + ct*16 + l16] = f2bf(p);
                    }
                } else {
                    #pragma unroll
                    for (int r = 0; r < 4; ++r) {
                        const int j   = jlo + l16;
                        const int row = row_base + quad*4 + r;
                        const float p = (j <= row) ? __builtin_amdgcn_exp2f(s[ct][r]) : 0.f;
                        lx[r] += p;
                        Pw[(quad*4 + r) * LDPP + ct*16 + l16] = f2bf(p);
                    }
                }
            }
            const bf16x8 pf0 = *(const bf16x8*)&Pw[l16 * LDPP + quad*8];
            const bf16x8 pf1 = *(const bf16x8*)&Pw[l16 * LDPP + 32 + quad*8];
            #pragma unroll
            for (int nt = 0; nt < 4; ++nt) {
                ox[nt] = __builtin_amdgcn_mfma_f32_16x16x32_bf16(pf0, vf[nt][0], ox[nt], 0,0,0);
                ox[nt] = __builtin_amdgcn_mfma_f32_16x16x32_bf16(pf1, vf[nt][1], ox[nt], 0,0,0);
            }
        }
    }

    #pragma unroll
    for (int r = 0; r < 4; ++r) {
        float x = la[r];
        x += __shfl_xor(x, 1, 16); x += __shfl_xor(x, 2, 16);
        x += __shfl_xor(x, 4, 16); x += __shfl_xor(x, 8, 16);
        la[r] = 1.0f / x;
        float y = lb[r];
        y += __shfl_xor(y, 1, 16); y += __shfl_xor(y, 2, 16);
        y += __shfl_xor(y, 4, 16); y += __shfl_xor(y, 8, 16);
        lb[r] = 1.0f / y;
    }
    // Y epilogue -> fragment-tiled layout:
    // row = b*NT + q0(+16) + quad*4 + r ; col = h*64 + nt*16 + l16
    const size_t Rbase = (size_t)((b*NT + q0) >> 4);   // subtile A row-tile
    #pragma unroll
    for (int nt = 0; nt < 4; ++nt) {
        const size_t tbase = (Rbase*32 + h*2 + (nt >> 1))*512
                           + (size_t)(((nt & 1)*2 + (l16 >> 3))*128 + (l16 & 7));
        #pragma unroll
        for (int r = 0; r < 4; ++r) {
            const size_t off = tbase + (quad*4 + r)*8;
            Y[off]         = f2bf(oa[nt][r] * la[r]);
            Y[off + 16384] = f2bf(ob[nt][r] * lb[r]);   // +1 row-tile (32*512)
        }
    }
}

__global__ __launch_bounds__(256) void flash_attn(
    const unsigned short* __restrict__ Qf,
    const unsigned short* __restrict__ Kf,
    const unsigned short* __restrict__ Vf,
    unsigned short* __restrict__ Y)
{
    __shared__ __align__(16) unsigned short Pl[4][16 * LDPP];
    const int tid  = threadIdx.x;
    const int wave = tid >> 6;
    const int lane = tid & 63;
    const int bh = blockIdx.y;
    const int w = blockIdx.x * 4 + wave;   // 0..31
    unsigned short* Pw = &Pl[wave][0];
    attn_q32(Qf, Kf, Vf, Y, Pw, bh, w, lane);
    attn_q32(Qf, Kf, Vf, Y, Pw, bh, 63 - w, lane);
}

// ---------------- launch ----------------
extern "C" void kernel_launch(void* const* d_in, const int* in_sizes, int n_in,
                              void* d_out, int out_size, void* d_ws, size_t ws_size,
                              hipStream_t stream) {
    const float* x  = (const float*)d_in[0];
    const float* Wq = (const float*)d_in[1];
    const float* bq = (const float*)d_in[2];
    const float* Wk = (const float*)d_in[3];
    const float* bk = (const float*)d_in[4];
    const float* Wv = (const float*)d_in[5];
    const float* bv = (const float*)d_in[6];
    const float* Wo = (const float*)d_in[7];
    const float* bo = (const float*)d_in[8];

    char* ws = (char*)d_ws;
    size_t off = 0;
    auto alloc = [&](size_t bytes) -> void* {
        void* p = ws + off;
        off += (bytes + 255) & ~(size_t)255;
        return p;
    };
    unsigned short* xb  = (unsigned short*)alloc((size_t)NM * NC * 2);
    unsigned short* Wqb = (unsigned short*)alloc((size_t)NC * NC * 2);
    unsigned short* Wkb = (unsigned short*)alloc((size_t)NC * NC * 2);
    unsigned short* Wvb = (unsigned short*)alloc((size_t)NC * NC * 2);
    unsigned short* Wob = (unsigned short*)alloc((size_t)NC * NC * 2);
    unsigned short* Qb  = (unsigned short*)alloc((size_t)NM * NC * 2);
    unsigned short* Kb  = (unsigned short*)alloc((size_t)NM * NC * 2);
    unsigned short* Vtb = (unsigned short*)alloc((size_t)NM * NC * 2);
    unsigned short* Yb  = (unsigned short*)alloc((size_t)NM * NC * 2);

    const int ntx = NM * NC / 512;   // 16384 tiles
    const int ntw = NC * NC / 512;   // 2048 tiles per weight
    cast_x_tiled<<<(ntx*64 + 255)/256, 256, 0, stream>>>(x, xb, ntx);
    cast4_tiled<<<dim3((ntw*64 + 255)/256, 4), 256, 0, stream>>>(
        Wq, Wk, Wv, Wo, Wqb, Wkb, Wvb, Wob, ntw);

    gemm_qkv<<<dim3(NM / TM, 24), 256, 0, stream>>>(
        xb, Wqb, Wkb, Wvb, bq, bk, bv, Qb, Kb, Vtb);

    flash_attn<<<dim3(8, NB*NH), 256, 0, stream>>>(Qb, Kb, Vtb, Yb);

    gemm_out<<<dim3(NM / TM, NC / TN), 256, 0, stream>>>(Yb, Wob, bo, (float*)d_out);
}

// Round 9
// 242.440 us; speedup vs baseline: 1.2967x; 1.0506x over previous
//
#include <hip/hip_runtime.h>
#include <hip/hip_bf16.h>
#include <stdint.h>

// Problem constants
#define NB 4
#define NT 2048
#define NC 1024
#define NH 16
#define NHD 64
#define NM (NB*NT)   // 8192 rows

typedef __attribute__((ext_vector_type(8))) __bf16 bf16x8;
typedef __attribute__((ext_vector_type(4))) float floatx4;
typedef __attribute__((ext_vector_type(8))) unsigned short ushortx8;

#define AS1(p) ((const __attribute__((address_space(1))) void*)(p))
#define AS3(p) ((__attribute__((address_space(3))) void*)(p))

__device__ __forceinline__ unsigned short f2bf(float f) {
    union { float f; unsigned int u; } v; v.f = f;
    unsigned int u = v.u;
    return (unsigned short)((u + 0x7FFFu + ((u >> 16) & 1u)) >> 16);
}
// pack two fp32 -> (bf16(hi)<<16)|bf16(lo), RTZ, single v_perm_b32
__device__ __forceinline__ unsigned int pk2(float lo, float hi) {
    union { float f; unsigned int u; } a, b; a.f = hi; b.f = lo;
    return __builtin_amdgcn_perm(a.u, b.u, 0x07060302u);
}

// ===== fragment-tiled layout (for all GEMM operands) =====
// matrix (rows x 1024 cols) stored as 16x32 tiles of 512 shorts:
//   tile (R=row/16, C=col/32) at offset (R*32 + C)*512
//   element (r=row&15, c=col&31) at ((c>>3)*16 + r)*8 + (c&7)

// ---------------- cast fp32 -> bf16, fragment-tiled (1 tile per wave) -------
__global__ void cast_x_tiled(const float* __restrict__ in,
                             unsigned short* __restrict__ out, int ntiles) {
    const int wid  = (blockIdx.x * blockDim.x + threadIdx.x) >> 6;
    const int lane = threadIdx.x & 63;
    if (wid >= ntiles) return;
    const int R = wid >> 5, C = wid & 31;
    const float* src = in + ((size_t)(R*16 + (lane >> 2)))*1024 + C*32 + (lane & 3)*8;
    const floatx4 v0 = *(const floatx4*)src;
    const floatx4 v1 = *(const floatx4*)(src + 4);
    ushortx8 o;
    o[0] = f2bf(v0[0]); o[1] = f2bf(v0[1]); o[2] = f2bf(v0[2]); o[3] = f2bf(v0[3]);
    o[4] = f2bf(v1[0]); o[5] = f2bf(v1[1]); o[6] = f2bf(v1[2]); o[7] = f2bf(v1[3]);
    *(ushortx8*)&out[(size_t)wid*512 + (((lane & 3)*16 + (lane >> 2)))*8] = o;
}

__global__ void cast4_tiled(const float* __restrict__ w0, const float* __restrict__ w1,
                            const float* __restrict__ w2, const float* __restrict__ w3,
                            unsigned short* __restrict__ o0, unsigned short* __restrict__ o1,
                            unsigned short* __restrict__ o2, unsigned short* __restrict__ o3,
                            int ntiles) {
    const int wid  = (blockIdx.x * blockDim.x + threadIdx.x) >> 6;
    const int lane = threadIdx.x & 63;
    if (wid >= ntiles) return;
    const float* in; unsigned short* out;
    switch (blockIdx.y) {
        case 0: in = w0; out = o0; break;
        case 1: in = w1; out = o1; break;
        case 2: in = w2; out = o2; break;
        default: in = w3; out = o3; break;
    }
    const int R = wid >> 5, C = wid & 31;
    const float* src = in + ((size_t)(R*16 + (lane >> 2)))*1024 + C*32 + (lane & 3)*8;
    const floatx4 v0 = *(const floatx4*)src;
    const floatx4 v1 = *(const floatx4*)(src + 4);
    ushortx8 o;
    o[0] = f2bf(v0[0]); o[1] = f2bf(v0[1]); o[2] = f2bf(v0[2]); o[3] = f2bf(v0[3]);
    o[4] = f2bf(v1[0]); o[5] = f2bf(v1[1]); o[6] = f2bf(v1[2]); o[7] = f2bf(v1[3]);
    *(ushortx8*)&out[(size_t)wid*512 + (((lane & 3)*16 + (lane >> 2)))*8] = o;
}

// ---------------- GEMM core: Out = (A @ W^T + bias) * oscale ----------------
// A, W fragment-tiled, K=1024. BK=32, 16KB LDS, conflict-free (r8).
// mode 0: Out fp32 row-major MxN (final projection)
// mode 1: Out bf16 in MFMA A/B-fragment order for Q/K
// mode 2: Out bf16 V^T A-frag order, key-permuted for the P^T PV scheme:
//         key slot within 32-group: q=(t>>2)&3, j=(t&3)+((t>>4)<<2)
#define TM 128
#define TN 128
#define BK 32

__device__ __forceinline__ void gemm_core(
    const unsigned short* __restrict__ A,
    const unsigned short* __restrict__ W,
    const float* __restrict__ bias,
    void* __restrict__ Out,
    unsigned short* As, unsigned short* Bs,
    int m_base, int n_base, int N_out, int K, int mode, float oscale)
{
    const int tid  = threadIdx.x;
    const int lane = tid & 63;
    const int wv   = tid >> 6;
    const int quad = lane >> 4;
    const int l16  = lane & 15;
    const int wm = (wv >> 1) * 64;
    const int wn = (wv & 1) * 64;

    floatx4 acc[4][4];
    #pragma unroll
    for (int i = 0; i < 4; ++i)
        #pragma unroll
        for (int j = 0; j < 4; ++j)
            acc[i][j] = (floatx4){0.f, 0.f, 0.f, 0.f};

    const int kTiles = K / BK;
    const int kct = K >> 5;

    const unsigned short* At = A + ((size_t)((m_base >> 4) + wv*2) * kct) * 512 + (size_t)lane*8;
    const unsigned short* Wt = W + ((size_t)((n_base >> 4) + wv*2) * kct) * 512 + (size_t)lane*8;
    const size_t rstride = (size_t)kct * 512;

    for (int kt = 0; kt < kTiles; ++kt) {
        __syncthreads();
        #pragma unroll
        for (int i = 0; i < 2; ++i) {
            __builtin_amdgcn_global_load_lds(
                AS1(At + (size_t)kt*512 + i*rstride),
                AS3(&As[(wv*2 + i)*512]), 16, 0, 0);
            __builtin_amdgcn_global_load_lds(
                AS1(Wt + (size_t)kt*512 + i*rstride),
                AS3(&Bs[(wv*2 + i)*512]), 16, 0, 0);
        }
        __syncthreads();

        bf16x8 af[4], bfr[4];
        #pragma unroll
        for (int mi = 0; mi < 4; ++mi)
            af[mi] = *(const bf16x8*)&As[((wv >> 1)*4 + mi)*512 + lane*8];
        #pragma unroll
        for (int ni = 0; ni < 4; ++ni)
            bfr[ni] = *(const bf16x8*)&Bs[((wv & 1)*4 + ni)*512 + lane*8];

        #pragma unroll
        for (int mi = 0; mi < 4; ++mi)
            #pragma unroll
            for (int ni = 0; ni < 4; ++ni)
                acc[mi][ni] = __builtin_amdgcn_mfma_f32_16x16x32_bf16(
                    af[mi], bfr[ni], acc[mi][ni], 0, 0, 0);
    }

    // epilogue: C/D layout col = lane&15, row = quad*4 + reg
    #pragma unroll
    for (int mi = 0; mi < 4; ++mi) {
        #pragma unroll
        for (int ni = 0; ni < 4; ++ni) {
            const int col = n_base + wn + ni*16 + l16;
            const float bv = bias[col & 1023];
            #pragma unroll
            for (int r = 0; r < 4; ++r) {
                const int row = m_base + wm + mi*16 + quad*4 + r;
                const float v = (acc[mi][ni][r] + bv) * oscale;
                if (mode == 0) {
                    ((float*)Out)[(size_t)row * N_out + col] = v;
                } else if (mode == 1) {
                    const int bb = row >> 11, t = row & (NT - 1);
                    const int h  = (col >> 6) & (NH - 1), d = col & 63;
                    const int bh = bb * NH + h;
                    const size_t idx =
                        ((size_t)((bh*128 + (t >> 4))*2 + (d >> 5)))*512
                        + (size_t)((((d >> 3) & 3)*16 + (t & 15))*8 + (d & 7));
                    ((unsigned short*)Out)[idx] = f2bf(v);
                } else {
                    const int bb = row >> 11, t = row & (NT - 1);
                    const int h  = (col >> 6) & (NH - 1), hd = col & 63;
                    const int bh = bb * NH + h;
                    const int tk = t & 31;
                    const int qv = (tk >> 2) & 3;
                    const int jv = (tk & 3) + ((tk >> 4) << 2);
                    const size_t idx =
                        ((size_t)((bh*64 + (t >> 5))*4 + (hd >> 4)))*512
                        + (size_t)((qv*16 + (hd & 15))*8 + jv);
                    ((unsigned short*)Out)[idx] = f2bf(v);
                }
            }
        }
    }
}

// Fused QKV: grid (64, 24); blockIdx.y: 0-7 Q, 8-15 K, 16-23 V
#define QSCALE (0.03125f * 1.44269504088896340736f)   // (1/sqrt(C)) * log2(e)

__global__ __launch_bounds__(256) void gemm_qkv(
    const unsigned short* __restrict__ A,
    const unsigned short* __restrict__ Wq, const unsigned short* __restrict__ Wk,
    const unsigned short* __restrict__ Wv,
    const float* __restrict__ bq, const float* __restrict__ bk,
    const float* __restrict__ bv,
    unsigned short* __restrict__ Qo, unsigned short* __restrict__ Ko,
    unsigned short* __restrict__ Vo)
{
    __shared__ __align__(16) unsigned short As[TM*BK];
    __shared__ __align__(16) unsigned short Bs[TN*BK];
    const int wi = blockIdx.y >> 3;
    const int n_base = (blockIdx.y & 7) * TN;
    const unsigned short* W; const float* bias; void* Out; int mode; float osc;
    if (wi == 0)      { W = Wq; bias = bq; Out = Qo; mode = 1; osc = QSCALE; }
    else if (wi == 1) { W = Wk; bias = bk; Out = Ko; mode = 1; osc = 1.0f; }
    else              { W = Wv; bias = bv; Out = Vo; mode = 2; osc = 1.0f; }
    gemm_core(A, W, bias, Out, As, Bs, blockIdx.x * TM, n_base, NC, NC, mode, osc);
}

__global__ __launch_bounds__(256) void gemm_out(
    const unsigned short* __restrict__ A,
    const unsigned short* __restrict__ W,
    const float* __restrict__ bias,
    float* __restrict__ Out)
{
    __shared__ __align__(16) unsigned short As[TM*BK];
    __shared__ __align__(16) unsigned short Bs[TN*BK];
    gemm_core(A, W, bias, Out, As, Bs, blockIdx.x * TM, blockIdx.y * TN,
              NC, NC, 0, 1.0f);
}

// ---------------- flash attention (causal), transposed-P scheme -------------
// S^T = mfma(A=K, B=Q) (identical fragment maps); C-layout of S^T: lane l16 =
// Q-row, quad*4+r = key. exp -> P^T; pack pairs (v_perm RTZ) directly into the
// B-operand of O^T = mfma(A=V^T(key-permuted), B=P^T). No LDS at all.
__device__ __forceinline__ void attn_q32(
    const unsigned short* __restrict__ Qf,
    const unsigned short* __restrict__ Kf,
    const unsigned short* __restrict__ Vf,
    unsigned short* __restrict__ Y,      // fragment-tiled (B*T x 1024)
    int bh, int st, int lane)
{
    const int quad = lane >> 4, l16 = lane & 15;
    const int q0 = st * 32;
    const int b = bh >> 4, h = bh & (NH - 1);

    const size_t qbase = ((size_t)(bh*128 + st*2))*1024 + (size_t)lane*8;
    const bf16x8 qa0 = *(const bf16x8*)&Qf[qbase];
    const bf16x8 qa1 = *(const bf16x8*)&Qf[qbase + 512];
    const bf16x8 qb0 = *(const bf16x8*)&Qf[qbase + 1024];
    const bf16x8 qb1 = *(const bf16x8*)&Qf[qbase + 1536];

    const unsigned short* kp = Kf + (size_t)bh*131072 + (size_t)lane*8;
    const unsigned short* vp = Vf + (size_t)bh*131072 + (size_t)lane*8;

    floatx4 oa[4], ob[4];
    #pragma unroll
    for (int nt = 0; nt < 4; ++nt) {
        oa[nt] = (floatx4){0.f,0.f,0.f,0.f};
        ob[nt] = (floatx4){0.f,0.f,0.f,0.f};
    }
    float la = 0.f, lb = 0.f;

    const int Ffull = q0 >> 6;
    const int ntile = Ffull + 1;          // full tiles + one diagonal tile

    for (int f = 0; f < ntile; ++f) {
        const int j0 = f * 64;
        const bool diag = (f == Ffull);
        bf16x8 kf[4][2], vf[4][2];
        {
            const unsigned short* kt = kp + (size_t)(j0 >> 4) * 1024;
            #pragma unroll
            for (int ct = 0; ct < 4; ++ct) {
                kf[ct][0] = *(const bf16x8*)&kt[ct*1024];
                kf[ct][1] = *(const bf16x8*)&kt[ct*1024 + 512];
            }
            const unsigned short* vt = vp + (size_t)(j0 >> 5) * 2048;
            #pragma unroll
            for (int nt = 0; nt < 4; ++nt) {
                vf[nt][0] = *(const bf16x8*)&vt[nt*512];
                vf[nt][1] = *(const bf16x8*)&vt[2048 + nt*512];
            }
        }
        #pragma unroll
        for (int sub = 0; sub < 2; ++sub) {
            const bf16x8 qx0 = sub ? qb0 : qa0;
            const bf16x8 qx1 = sub ? qb1 : qa1;
            floatx4* ox = sub ? ob : oa;

            floatx4 s[4];
            #pragma unroll
            for (int ct = 0; ct < 4; ++ct) {
                s[ct] = (floatx4){0.f,0.f,0.f,0.f};
                s[ct] = __builtin_amdgcn_mfma_f32_16x16x32_bf16(kf[ct][0], qx0, s[ct], 0,0,0);
                s[ct] = __builtin_amdgcn_mfma_f32_16x16x32_bf16(kf[ct][1], qx1, s[ct], 0,0,0);
            }
            float p[4][4];
            float lsum = 0.f;
            if (!diag) {
                #pragma unroll
                for (int ct = 0; ct < 4; ++ct)
                    #pragma unroll
                    for (int r = 0; r < 4; ++r) {
                        p[ct][r] = __builtin_amdgcn_exp2f(s[ct][r]);
                        lsum += p[ct][r];
                    }
            } else {
                const int row = q0 + sub*16 + l16;
                #pragma unroll
                for (int ct = 0; ct < 4; ++ct)
                    #pragma unroll
                    for (int r = 0; r < 4; ++r) {
                        const int key = j0 + ct*16 + quad*4 + r;
                        p[ct][r] = (key <= row) ? __builtin_amdgcn_exp2f(s[ct][r]) : 0.f;
                        lsum += p[ct][r];
                    }
            }
            if (sub) lb += lsum; else la += lsum;

            union { bf16x8 v; unsigned int u[4]; } pf0, pf1;
            pf0.u[0] = pk2(p[0][0], p[0][1]); pf0.u[1] = pk2(p[0][2], p[0][3]);
            pf0.u[2] = pk2(p[1][0], p[1][1]); pf0.u[3] = pk2(p[1][2], p[1][3]);
            pf1.u[0] = pk2(p[2][0], p[2][1]); pf1.u[1] = pk2(p[2][2], p[2][3]);
            pf1.u[2] = pk2(p[3][0], p[3][1]); pf1.u[3] = pk2(p[3][2], p[3][3]);

            #pragma unroll
            for (int nt = 0; nt < 4; ++nt) {
                ox[nt] = __builtin_amdgcn_mfma_f32_16x16x32_bf16(vf[nt][0], pf0.v, ox[nt], 0,0,0);
                ox[nt] = __builtin_amdgcn_mfma_f32_16x16x32_bf16(vf[nt][1], pf1.v, ox[nt], 0,0,0);
            }
        }
    }

    // row-sum: reduce across quads only (lanes with same l16)
    la += __shfl_xor(la, 16); la += __shfl_xor(la, 32);
    lb += __shfl_xor(lb, 16); lb += __shfl_xor(lb, 32);
    const float ia = 1.0f / la, ib = 1.0f / lb;

    // O^T element: hd = nt*16 + quad*4 + r, row-in-subtile = l16.
    // Y fragment-tiled: 4 consecutive c per (nt,quad) -> one 8B store.
    const size_t Rbase = (size_t)((b*NT + q0) >> 4);
    const int cg = (quad >> 1), co = (quad & 1)*4;
    #pragma unroll
    for (int nt = 0; nt < 4; ++nt) {
        const size_t base = ((Rbase*32 + h*2 + (nt >> 1))*512)
                          + (size_t)((((nt & 1)*2 + cg)*16 + l16)*8 + co);
        ushort4 wa, wb;
        wa.x = f2bf(oa[nt][0]*ia); wa.y = f2bf(oa[nt][1]*ia);
        wa.z = f2bf(oa[nt][2]*ia); wa.w = f2bf(oa[nt][3]*ia);
        wb.x = f2bf(ob[nt][0]*ib); wb.y = f2bf(ob[nt][1]*ib);
        wb.z = f2bf(ob[nt][2]*ib); wb.w = f2bf(ob[nt][3]*ib);
        *(ushort4*)&Y[base]         = wa;
        *(ushort4*)&Y[base + 16384] = wb;   // +1 row-tile (32*512)
    }
}

__global__ __launch_bounds__(256) void flash_attn(
    const unsigned short* __restrict__ Qf,
    const unsigned short* __restrict__ Kf,
    const unsigned short* __restrict__ Vf,
    unsigned short* __restrict__ Y)
{
    const int tid  = threadIdx.x;
    const int wave = tid >> 6;
    const int lane = tid & 63;
    const int bh = blockIdx.y;
    const int w = blockIdx.x * 4 + wave;   // 0..31
    attn_q32(Qf, Kf, Vf, Y, bh, w, lane);
    attn_q32(Qf, Kf, Vf, Y, bh, 63 - w, lane);
}

// ---------------- launch ----------------
extern "C" void kernel_launch(void* const* d_in, const int* in_sizes, int n_in,
                              void* d_out, int out_size, void* d_ws, size_t ws_size,
                              hipStream_t stream) {
    const float* x  = (const float*)d_in[0];
    const float* Wq = (const float*)d_in[1];
    const float* bq = (const float*)d_in[2];
    const float* Wk = (const float*)d_in[3];
    const float* bk = (const float*)d_in[4];
    const float* Wv = (const float*)d_in[5];
    const float* bv = (const float*)d_in[6];
    const float* Wo = (const float*)d_in[7];
    const float* bo = (const float*)d_in[8];

    char* ws = (char*)d_ws;
    size_t off = 0;
    auto alloc = [&](size_t bytes) -> void* {
        void* p = ws + off;
        off += (bytes + 255) & ~(size_t)255;
        return p;
    };
    unsigned short* xb  = (unsigned short*)alloc((size_t)NM * NC * 2);
    unsigned short* Wqb = (unsigned short*)alloc((size_t)NC * NC * 2);
    unsigned short* Wkb = (unsigned short*)alloc((size_t)NC * NC * 2);
    unsigned short* Wvb = (unsigned short*)alloc((size_t)NC * NC * 2);
    unsigned short* Wob = (unsigned short*)alloc((size_t)NC * NC * 2);
    unsigned short* Qb  = (unsigned short*)alloc((size_t)NM * NC * 2);
    unsigned short* Kb  = (unsigned short*)alloc((size_t)NM * NC * 2);
    unsigned short* Vtb = (unsigned short*)alloc((size_t)NM * NC * 2);
    unsigned short* Yb  = (unsigned short*)alloc((size_t)NM * NC * 2);

    const int ntx = NM * NC / 512;   // 16384 tiles
    const int ntw = NC * NC / 512;   // 2048 tiles per weight
    cast_x_tiled<<<(ntx*64 + 255)/256, 256, 0, stream>>>(x, xb, ntx);
    cast4_tiled<<<dim3((ntw*64 + 255)/256, 4), 256, 0, stream>>>(
        Wq, Wk, Wv, Wo, Wqb, Wkb, Wvb, Wob, ntw);

    gemm_qkv<<<dim3(NM / TM, 24), 256, 0, stream>>>(
        xb, Wqb, Wkb, Wvb, bq, bk, bv, Qb, Kb, Vtb);

    flash_attn<<<dim3(8, NB*NH), 256, 0, stream>>>(Qb, Kb, Vtb, Yb);

    gemm_out<<<dim3(NM / TM, NC / TN), 256, 0, stream>>>(Yb, Wob, bo, (float*)d_out);
}